// Round 1
// baseline (14808.641 us; speedup 1.0000x reference)
//
#include <hip/hip_runtime.h>
#include <hip/hip_bf16.h>

typedef unsigned short u16;
typedef __bf16 bf16x8 __attribute__((ext_vector_type(8)));
typedef float   f32x4 __attribute__((ext_vector_type(4)));
typedef unsigned short u16x8 __attribute__((ext_vector_type(8)));

#define NTOK  16384
#define HID_  1280
#define NHEAD 16
#define HD    80
#define INTER_ 3456
#define NGRP  4096
#define ODIM  2048
#define BIGD  5120

static __device__ __forceinline__ u16 f2bf(float f) {
  __hip_bfloat16 h = __float2bfloat16(f);
  return __builtin_bit_cast(u16, h);
}
static __device__ __forceinline__ float bf2f(u16 u) {
  return __bfloat162float(__builtin_bit_cast(__hip_bfloat16, u));
}
static __device__ __forceinline__ float gelu_tanh(float x) {
  float x3 = x * x * x;
  return 0.5f * x * (1.0f + tanhf(0.7978845608028654f * (x + 0.044715f * x3)));
}

// ---------------------------------------------------------------- gathers
__global__ __launch_bounds__(256) void gather_pv_k(
    const float* __restrict__ pv, const int* __restrict__ wi, u16* __restrict__ out) {
  int t = blockIdx.x * 256 + threadIdx.x;          // NTOK*384 float4 groups
  if (t >= NTOK * 384) return;
  int i = t / 384, c4 = t - i * 384;
  int s = wi[i >> 2] * 4 + (i & 3);
  float4 v = *(const float4*)(pv + (size_t)s * 1536 + c4 * 4);
  uint2 r;
  r.x = (unsigned)f2bf(v.x) | ((unsigned)f2bf(v.y) << 16);
  r.y = (unsigned)f2bf(v.z) | ((unsigned)f2bf(v.w) << 16);
  *(uint2*)(out + (size_t)i * 1536 + c4 * 4) = r;
}

__global__ __launch_bounds__(256) void gather_cs_k(
    const float* __restrict__ ci, const float* __restrict__ si,
    const int* __restrict__ wi, float* __restrict__ co, float* __restrict__ so) {
  int t = blockIdx.x * 256 + threadIdx.x;          // NTOK*20 float4 groups
  if (t >= NTOK * 20) return;
  int i = t / 20, c4 = t - i * 20;
  int s = wi[i >> 2] * 4 + (i & 3);
  *(float4*)(co + (size_t)i * 80 + c4 * 4) = *(const float4*)(ci + (size_t)s * 80 + c4 * 4);
  *(float4*)(so + (size_t)i * 80 + c4 * 4) = *(const float4*)(si + (size_t)s * 80 + c4 * 4);
}

// ---------------------------------------------------------------- rmsnorm (f32 in -> bf16 out)
__global__ __launch_bounds__(256) void rmsnorm_k(
    const float* __restrict__ x, const float* __restrict__ w, u16* __restrict__ out, int D) {
  int row = blockIdx.x;
  const float* xr = x + (size_t)row * D;
  float ss = 0.f;
  for (int c = threadIdx.x; c < D; c += 256) { float v = xr[c]; ss += v * v; }
  #pragma unroll
  for (int d = 1; d < 64; d <<= 1) ss += __shfl_xor(ss, d, 64);
  __shared__ float part[4];
  if ((threadIdx.x & 63) == 0) part[threadIdx.x >> 6] = ss;
  __syncthreads();
  float tot = part[0] + part[1] + part[2] + part[3];
  float scale = rsqrtf(tot / (float)D + 1e-6f);
  u16* orow = out + (size_t)row * D;
  for (int c = threadIdx.x; c < D; c += 256) orow[c] = f2bf(xr[c] * scale * w[c]);
}

// ---------------------------------------------------------------- GEMM: C = A(bf16) @ B(f32 K x N) + bias
// MODE 0: store bf16; 1: store f32; 2: f32 +=; 3: gelu->bf16; 4: f32 scatter rows via rowmap
template <int MODE>
__global__ __launch_bounds__(256, 2) void gemm_k(
    const u16* __restrict__ A, const float* __restrict__ B, const float* __restrict__ bias,
    void* __restrict__ outp, const int* __restrict__ rowmap, int M, int N, int K) {
  __shared__ u16 As[128 * 40];
  __shared__ u16 Bs[128 * 40];
  const int tid = threadIdx.x;
  const int bm = blockIdx.y, bn = blockIdx.x;
  const int lane = tid & 63, wv = tid >> 6;
  const int wm = wv >> 1, wn = wv & 1;
  const int lr = lane & 15, lk = lane >> 4;

  const int arow = tid >> 2;           // 0..63
  const int akq = (tid & 3) * 8;       // 0,8,16,24
  const int brow = (tid >> 4) * 2;     // 0..30
  const int bcol = (tid & 15) * 8;     // 0..120

  const u16* Ag = A + (size_t)(bm * 128 + arow) * K + akq;
  const u16* Ag2 = Ag + (size_t)64 * K;
  const float* Bg = B + (size_t)brow * N + bn * 128 + bcol;

  f32x4 acc[4][4];
  #pragma unroll
  for (int i = 0; i < 4; i++)
    #pragma unroll
    for (int j = 0; j < 4; j++) { acc[i][j][0] = 0.f; acc[i][j][1] = 0.f; acc[i][j][2] = 0.f; acc[i][j][3] = 0.f; }

  for (int k0 = 0; k0 < K; k0 += 32) {
    uint4 a0 = *(const uint4*)(Ag + k0);
    uint4 a1 = *(const uint4*)(Ag2 + k0);
    const float* bp = Bg + (size_t)k0 * N;
    float4 b00 = *(const float4*)(bp);
    float4 b01 = *(const float4*)(bp + 4);
    float4 b10 = *(const float4*)(bp + N);
    float4 b11 = *(const float4*)(bp + N + 4);
    __syncthreads();
    *(uint4*)&As[arow * 40 + akq] = a0;
    *(uint4*)&As[(arow + 64) * 40 + akq] = a1;
    float r0a[8] = {b00.x, b00.y, b00.z, b00.w, b01.x, b01.y, b01.z, b01.w};
    float r1a[8] = {b10.x, b10.y, b10.z, b10.w, b11.x, b11.y, b11.z, b11.w};
    #pragma unroll
    for (int j = 0; j < 8; j++) {
      unsigned pk = (unsigned)f2bf(r0a[j]) | ((unsigned)f2bf(r1a[j]) << 16);
      *(unsigned*)&Bs[(bcol + j) * 40 + brow] = pk;
    }
    __syncthreads();
    bf16x8 af[4], bfr[4];
    #pragma unroll
    for (int f = 0; f < 4; f++) {
      af[f] = *(const bf16x8*)&As[(wm * 64 + f * 16 + lr) * 40 + lk * 8];
      bfr[f] = *(const bf16x8*)&Bs[(wn * 64 + f * 16 + lr) * 40 + lk * 8];
    }
    #pragma unroll
    for (int fm = 0; fm < 4; fm++)
      #pragma unroll
      for (int fn = 0; fn < 4; fn++)
        acc[fm][fn] = __builtin_amdgcn_mfma_f32_16x16x32_bf16(af[fm], bfr[fn], acc[fm][fn], 0, 0, 0);
  }

  const int rbase = bm * 128 + wm * 64;
  const int cbase = bn * 128 + wn * 64;
  #pragma unroll
  for (int fn = 0; fn < 4; fn++) {
    int Cc = cbase + fn * 16 + lr;
    float bv = bias ? bias[Cc] : 0.f;
    #pragma unroll
    for (int fm = 0; fm < 4; fm++) {
      #pragma unroll
      for (int j = 0; j < 4; j++) {
        int R = rbase + fm * 16 + lk * 4 + j;
        float v = acc[fm][fn][j] + bv;
        if (MODE == 0) {
          ((u16*)outp)[(size_t)R * N + Cc] = f2bf(v);
        } else if (MODE == 1) {
          ((float*)outp)[(size_t)R * N + Cc] = v;
        } else if (MODE == 2) {
          ((float*)outp)[(size_t)R * N + Cc] += v;
        } else if (MODE == 3) {
          ((u16*)outp)[(size_t)R * N + Cc] = f2bf(gelu_tanh(v));
        } else {
          int orow = rowmap[R];
          ((float*)outp)[(size_t)orow * N + Cc] = v;
        }
      }
    }
  }
}

// ---------------------------------------------------------------- RoPE (q,k) on bf16 qkv
__global__ __launch_bounds__(256) void rope_k(
    const u16* __restrict__ qkv, u16* __restrict__ qkvr,
    const float* __restrict__ cosr, const float* __restrict__ sinr) {
  int t = blockIdx.x * 256 + threadIdx.x;          // NTOK*640
  if (t >= NTOK * 640) return;
  int i = t / 640, j = t - i * 640;
  int head = j / 40, d = j - head * 40;
  size_t base = (size_t)i * 3840 + head * 80 + d;
  float c0 = cosr[i * 80 + d], c1 = cosr[i * 80 + 40 + d];
  float s0 = sinr[i * 80 + d], s1 = sinr[i * 80 + 40 + d];
  float q0 = bf2f(qkv[base]), q1 = bf2f(qkv[base + 40]);
  qkvr[base] = f2bf(q0 * c0 - q1 * s0);
  qkvr[base + 40] = f2bf(q1 * c1 + q0 * s1);
  float k0 = bf2f(qkv[base + 1280]), k1 = bf2f(qkv[base + 1320]);
  qkvr[base + 1280] = f2bf(k0 * c0 - k1 * s0);
  qkvr[base + 1320] = f2bf(k1 * c1 + k0 * s1);
}

__global__ __launch_bounds__(256) void copyv_k(const u16* __restrict__ qkv, u16* __restrict__ qkvr) {
  int t = blockIdx.x * 256 + threadIdx.x;          // NTOK*160 uint4s
  if (t >= NTOK * 160) return;
  int i = t / 160, c = t - i * 160;
  size_t off = (size_t)i * 3840 + 2560 + (size_t)c * 8;
  *(uint4*)(qkvr + off) = *(const uint4*)(qkv + off);
}

// ---------------------------------------------------------------- windowed attention, MFMA
// one block per (window, head); 64 tokens, head_dim 80 (K padded to 96)
__global__ __launch_bounds__(256, 2) void attn_k(
    const u16* __restrict__ qkvr, u16* __restrict__ outO) {
  __shared__ u16 Qs[64 * 104];
  __shared__ u16 Ks[64 * 104];
  __shared__ u16 Vt[80 * 72];
  __shared__ u16 Ps[64 * 72];
  const int w = blockIdx.x, hd = blockIdx.y;
  const int tid = threadIdx.x;
  const u16* base = qkvr + (size_t)w * 64 * 3840 + hd * 80;

  for (int idx = tid; idx < 64 * 96; idx += 256) {
    int r = idx / 96, c = idx - r * 96;
    u16 qv = 0, kv = 0;
    if (c < 80) { qv = base[(size_t)r * 3840 + c]; kv = base[(size_t)r * 3840 + 1280 + c]; }
    Qs[r * 104 + c] = qv;
    Ks[r * 104 + c] = kv;
  }
  for (int idx = tid; idx < 80 * 64; idx += 256) {
    int d = idx >> 6, kt = idx & 63;
    Vt[d * 72 + kt] = base[(size_t)kt * 3840 + 2560 + d];
  }
  __syncthreads();

  const int lane = tid & 63, wv = tid >> 6;
  const int lr = lane & 15, lk = lane >> 4;
  const float sc = 0.11180339887498949f;  // 80^-0.5

  f32x4 sfrag[4];
  #pragma unroll
  for (int f = 0; f < 4; f++) { sfrag[f][0] = 0.f; sfrag[f][1] = 0.f; sfrag[f][2] = 0.f; sfrag[f][3] = 0.f; }
  bf16x8 aq[3];
  #pragma unroll
  for (int ks = 0; ks < 3; ks++) aq[ks] = *(const bf16x8*)&Qs[(wv * 16 + lr) * 104 + ks * 32 + lk * 8];
  #pragma unroll
  for (int fn = 0; fn < 4; fn++) {
    #pragma unroll
    for (int ks = 0; ks < 3; ks++) {
      bf16x8 bk = *(const bf16x8*)&Ks[(fn * 16 + lr) * 104 + ks * 32 + lk * 8];
      sfrag[fn] = __builtin_amdgcn_mfma_f32_16x16x32_bf16(aq[ks], bk, sfrag[fn], 0, 0, 0);
    }
  }

  float inv[4];
  #pragma unroll
  for (int j = 0; j < 4; j++) {
    float mx = -1e30f;
    #pragma unroll
    for (int fn = 0; fn < 4; fn++) mx = fmaxf(mx, sfrag[fn][j] * sc);
    #pragma unroll
    for (int d = 1; d < 16; d <<= 1) mx = fmaxf(mx, __shfl_xor(mx, d, 64));
    float sum = 0.f;
    #pragma unroll
    for (int fn = 0; fn < 4; fn++) {
      float e = __expf(sfrag[fn][j] * sc - mx);
      Ps[(wv * 16 + lk * 4 + j) * 72 + fn * 16 + lr] = f2bf(e);
      sum += e;
    }
    #pragma unroll
    for (int d = 1; d < 16; d <<= 1) sum += __shfl_xor(sum, d, 64);
    inv[j] = 1.0f / sum;
  }

  bf16x8 ap[2];
  #pragma unroll
  for (int ks = 0; ks < 2; ks++) ap[ks] = *(const bf16x8*)&Ps[(wv * 16 + lr) * 72 + ks * 32 + lk * 8];
  f32x4 of[5];
  #pragma unroll
  for (int f = 0; f < 5; f++) { of[f][0] = 0.f; of[f][1] = 0.f; of[f][2] = 0.f; of[f][3] = 0.f; }
  #pragma unroll
  for (int fn2 = 0; fn2 < 5; fn2++) {
    #pragma unroll
    for (int ks = 0; ks < 2; ks++) {
      bf16x8 bv = *(const bf16x8*)&Vt[(fn2 * 16 + lr) * 72 + ks * 32 + lk * 8];
      of[fn2] = __builtin_amdgcn_mfma_f32_16x16x32_bf16(ap[ks], bv, of[fn2], 0, 0, 0);
    }
  }

  #pragma unroll
  for (int fn2 = 0; fn2 < 5; fn2++) {
    #pragma unroll
    for (int j = 0; j < 4; j++) {
      int q = wv * 16 + lk * 4 + j;
      int d = fn2 * 16 + lr;
      outO[((size_t)(w * 64 + q)) * 1280 + hd * 80 + d] = f2bf(of[fn2][j] * inv[j]);
    }
  }
}

// ---------------------------------------------------------------- silu(g)*u, in place into g
__global__ __launch_bounds__(256) void silumul_k(u16* __restrict__ g, const u16* __restrict__ u) {
  int t = blockIdx.x * 256 + threadIdx.x;          // NTOK*432 groups of 8
  if (t >= NTOK * 432) return;
  u16x8 gv = *(const u16x8*)(g + (size_t)t * 8);
  u16x8 uv = *(const u16x8*)(u + (size_t)t * 8);
  u16x8 o;
  #pragma unroll
  for (int e = 0; e < 8; e++) {
    float x = bf2f(gv[e]), y = bf2f(uv[e]);
    float s = x / (1.f + __expf(-x));
    o[e] = f2bf(s * y);
  }
  *(u16x8*)(g + (size_t)t * 8) = o;
}

// ---------------------------------------------------------------- host
extern "C" void kernel_launch(void* const* d_in, const int* in_sizes, int n_in,
                              void* d_out, int out_size, void* d_ws, size_t ws_size,
                              hipStream_t stream) {
  (void)in_sizes; (void)n_in; (void)out_size; (void)ws_size;
  const float* pv   = (const float*)d_in[0];
  const float* cosi = (const float*)d_in[1];
  const float* sini = (const float*)d_in[2];
  const int*   wi   = (const int*)d_in[3];
  const float* Wp   = (const float*)d_in[4];
  const float* n1w  = (const float*)d_in[5];
  const float* qkvw = (const float*)d_in[6];
  const float* qkvb = (const float*)d_in[7];
  const float* pw   = (const float*)d_in[8];
  const float* pb   = (const float*)d_in[9];
  const float* n2w  = (const float*)d_in[10];
  const float* gw   = (const float*)d_in[11];
  const float* gb   = (const float*)d_in[12];
  const float* uw   = (const float*)d_in[13];
  const float* ub   = (const float*)d_in[14];
  const float* dw   = (const float*)d_in[15];
  const float* db   = (const float*)d_in[16];
  const float* mnw  = (const float*)d_in[17];
  const float* ml1w = (const float*)d_in[18];
  const float* ml1b = (const float*)d_in[19];
  const float* ml2w = (const float*)d_in[20];
  const float* ml2b = (const float*)d_in[21];
  const float* dnw  = (const float*)d_in[22];
  const float* dl1w = (const float*)d_in[23];
  const float* dl1b = (const float*)d_in[24];
  const float* dl2w = (const float*)d_in[25];
  const float* dl2b = (const float*)d_in[26];
  float* outv = (float*)d_out;
  char* ws = (char*)d_ws;

  size_t off = 0;
  float* h    = (float*)(ws + off); off += (size_t)NTOK * HID_ * 4;     // 83.9MB
  float* cosr = (float*)(ws + off); off += (size_t)NTOK * 80 * 4;
  float* sinr = (float*)(ws + off); off += (size_t)NTOK * 80 * 4;
  u16*  xb    = (u16*)(ws + off);  off += (size_t)NTOK * HID_ * 2;      // 41.9MB
  u16*  bufA  = (u16*)(ws + off);  off += (size_t)NTOK * 3840 * 2;      // 125.8MB
  u16*  bufB  = (u16*)(ws + off);  off += (size_t)NTOK * 3840 * 2;      // 125.8MB
  u16*  bufC  = (u16*)(ws + off);  off += (size_t)NTOK * HID_ * 2;      // 41.9MB

  dim3 B256(256);

  // gather pixel rows (into bufA as pv_g) + cos/sin
  gather_pv_k<<<(NTOK * 384 + 255) / 256, B256, 0, stream>>>(pv, wi, bufA);
  gather_cs_k<<<(NTOK * 20 + 255) / 256, B256, 0, stream>>>(cosi, sini, wi, cosr, sinr);

  // h = pv_g @ W_patch   (f32 out)
  gemm_k<1><<<dim3(HID_ / 128, NTOK / 128), B256, 0, stream>>>(bufA, Wp, nullptr, h, nullptr, NTOK, HID_, 1536);

  for (int i = 0; i < 6; i++) {
    // attn
    rmsnorm_k<<<NTOK, B256, 0, stream>>>(h, n1w + (size_t)i * HID_, xb, HID_);
    gemm_k<0><<<dim3(3840 / 128, NTOK / 128), B256, 0, stream>>>(
        xb, qkvw + (size_t)i * HID_ * 3840, qkvb + (size_t)i * 3840, bufA, nullptr, NTOK, 3840, HID_);
    rope_k<<<(NTOK * 640 + 255) / 256, B256, 0, stream>>>(bufA, bufB, cosr, sinr);
    copyv_k<<<(NTOK * 160 + 255) / 256, B256, 0, stream>>>(bufA, bufB);
    attn_k<<<dim3(256, 16), B256, 0, stream>>>(bufB, bufC);
    gemm_k<2><<<dim3(HID_ / 128, NTOK / 128), B256, 0, stream>>>(
        bufC, pw + (size_t)i * HID_ * HID_, pb + (size_t)i * HID_, h, nullptr, NTOK, HID_, HID_);
    // mlp
    rmsnorm_k<<<NTOK, B256, 0, stream>>>(h, n2w + (size_t)i * HID_, xb, HID_);
    gemm_k<0><<<dim3(INTER_ / 128, NTOK / 128), B256, 0, stream>>>(
        xb, gw + (size_t)i * HID_ * INTER_, gb + (size_t)i * INTER_, bufA, nullptr, NTOK, INTER_, HID_);
    gemm_k<0><<<dim3(INTER_ / 128, NTOK / 128), B256, 0, stream>>>(
        xb, uw + (size_t)i * HID_ * INTER_, ub + (size_t)i * INTER_, bufB, nullptr, NTOK, INTER_, HID_);
    silumul_k<<<(NTOK * 432 + 255) / 256, B256, 0, stream>>>(bufA, bufB);
    gemm_k<2><<<dim3(HID_ / 128, NTOK / 128), B256, 0, stream>>>(
        bufA, dw + (size_t)i * INTER_ * HID_, db + (size_t)i * HID_, h, nullptr, NTOK, HID_, INTER_);
    // deepstack mergers after layers 2 and 4
    if (i == 2 || i == 4) {
      int j = (i == 2) ? 0 : 1;
      rmsnorm_k<<<NGRP, B256, 0, stream>>>(h, dnw + (size_t)j * BIGD, bufC, BIGD);
      gemm_k<3><<<dim3(BIGD / 128, NGRP / 128), B256, 0, stream>>>(
          bufC, dl1w + (size_t)j * BIGD * BIGD, dl1b + (size_t)j * BIGD, bufA, nullptr, NGRP, BIGD, BIGD);
      gemm_k<4><<<dim3(ODIM / 128, NGRP / 128), B256, 0, stream>>>(
          bufA, dl2w + (size_t)j * BIGD * ODIM, dl2b + (size_t)j * ODIM,
          outv + (size_t)(1 + j) * NGRP * ODIM, wi, NGRP, ODIM, BIGD);
    }
  }

  // final merger -> plane 0
  rmsnorm_k<<<NTOK, B256, 0, stream>>>(h, mnw, bufC, HID_);
  gemm_k<3><<<dim3(BIGD / 128, NGRP / 128), B256, 0, stream>>>(
      bufC, ml1w, ml1b, bufA, nullptr, NGRP, BIGD, BIGD);
  gemm_k<4><<<dim3(ODIM / 128, NGRP / 128), B256, 0, stream>>>(
      bufA, ml2w, ml2b, outv, wi, NGRP, ODIM, BIGD);
}

// Round 3
// 10350.357 us; speedup vs baseline: 1.4307x; 1.4307x over previous
//
#include <hip/hip_runtime.h>
#include <hip/hip_bf16.h>

typedef unsigned short u16;
typedef __bf16 bf16x8 __attribute__((ext_vector_type(8)));
typedef float   f32x4 __attribute__((ext_vector_type(4)));
typedef unsigned short u16x8 __attribute__((ext_vector_type(8)));

#define NTOK  16384
#define HID_  1280
#define NHEAD 16
#define HD    80
#define INTER_ 3456
#define NGRP  4096
#define ODIM  2048
#define BIGD  5120

static __device__ __forceinline__ u16 f2bf(float f) {
  __hip_bfloat16 h = __float2bfloat16(f);
  return __builtin_bit_cast(u16, h);
}
static __device__ __forceinline__ float bf2f(u16 u) {
  return __bfloat162float(__builtin_bit_cast(__hip_bfloat16, u));
}
static __device__ __forceinline__ float gelu_tanh(float x) {
  float x3 = x * x * x;
  return 0.5f * x * (1.0f + tanhf(0.7978845608028654f * (x + 0.044715f * x3)));
}

// async global->LDS, 16B per lane, dest = wave-uniform base + lane*16
static __device__ __forceinline__ void gload_lds16(const u16* g, u16* l) {
  __builtin_amdgcn_global_load_lds(
      (const __attribute__((address_space(1))) unsigned int*)g,
      (__attribute__((address_space(3))) unsigned int*)l, 16, 0, 0);
}

// ---------------------------------------------------------------- gathers
__global__ __launch_bounds__(256) void gather_pv_k(
    const float* __restrict__ pv, const int* __restrict__ wi, u16* __restrict__ out) {
  int t = blockIdx.x * 256 + threadIdx.x;          // NTOK*384 float4 groups
  if (t >= NTOK * 384) return;
  int i = t / 384, c4 = t - i * 384;
  int s = wi[i >> 2] * 4 + (i & 3);
  float4 v = *(const float4*)(pv + (size_t)s * 1536 + c4 * 4);
  uint2 r;
  r.x = (unsigned)f2bf(v.x) | ((unsigned)f2bf(v.y) << 16);
  r.y = (unsigned)f2bf(v.z) | ((unsigned)f2bf(v.w) << 16);
  *(uint2*)(out + (size_t)i * 1536 + c4 * 4) = r;
}

__global__ __launch_bounds__(256) void gather_cs_k(
    const float* __restrict__ ci, const float* __restrict__ si,
    const int* __restrict__ wi, float* __restrict__ co, float* __restrict__ so) {
  int t = blockIdx.x * 256 + threadIdx.x;          // NTOK*20 float4 groups
  if (t >= NTOK * 20) return;
  int i = t / 20, c4 = t - i * 20;
  int s = wi[i >> 2] * 4 + (i & 3);
  *(float4*)(co + (size_t)i * 80 + c4 * 4) = *(const float4*)(ci + (size_t)s * 80 + c4 * 4);
  *(float4*)(so + (size_t)i * 80 + c4 * 4) = *(const float4*)(si + (size_t)s * 80 + c4 * 4);
}

// ---------------------------------------------------------------- weight f32[K][N] -> bf16[N][K]
__global__ __launch_bounds__(256) void twt_k(
    const float* __restrict__ W, u16* __restrict__ Wt, int K, int N) {
  __shared__ u16 t[32][33];
  int bn = blockIdx.x * 32, bk = blockIdx.y * 32;
  int tx = threadIdx.x & 31, ty = threadIdx.x >> 5;   // ty 0..7
  #pragma unroll
  for (int r = 0; r < 4; r++) {
    int k = bk + ty + r * 8;
    t[tx][ty + r * 8] = f2bf(W[(size_t)k * N + bn + tx]);
  }
  __syncthreads();
  #pragma unroll
  for (int r = 0; r < 4; r++) {
    int n = bn + ty + r * 8;
    Wt[(size_t)n * K + bk + tx] = t[ty + r * 8][tx];
  }
}

// ---------------------------------------------------------------- rmsnorm (f32 in -> bf16 out)
__global__ __launch_bounds__(256) void rmsnorm_k(
    const float* __restrict__ x, const float* __restrict__ w, u16* __restrict__ out, int D) {
  int row = blockIdx.x;
  const float* xr = x + (size_t)row * D;
  float ss = 0.f;
  for (int c = threadIdx.x; c < D; c += 256) { float v = xr[c]; ss += v * v; }
  #pragma unroll
  for (int d = 1; d < 64; d <<= 1) ss += __shfl_xor(ss, d, 64);
  __shared__ float part[4];
  if ((threadIdx.x & 63) == 0) part[threadIdx.x >> 6] = ss;
  __syncthreads();
  float tot = part[0] + part[1] + part[2] + part[3];
  float scale = rsqrtf(tot / (float)D + 1e-6f);
  u16* orow = out + (size_t)row * D;
  for (int c = threadIdx.x; c < D; c += 256) orow[c] = f2bf(xr[c] * scale * w[c]);
}

// ---------------------------------------------------------------- GEMM: C = A(bf16 [M][K]) @ Bt(bf16 [N][K])^T + bias
// m97 structure: 128x128 tile, BK=32, global_load_lds w16, swizzled LDS.
// MODE 0: store bf16; 1: store f32; 2: f32 +=; 3: gelu->bf16; 4: f32 scatter rows via rowmap
template <int MODE>
__global__ __launch_bounds__(256, 2) void gemm2_k(
    const u16* __restrict__ A, const u16* __restrict__ Bt, const float* __restrict__ bias,
    void* __restrict__ outp, const int* __restrict__ rowmap, int N, int K) {
  __shared__ __align__(16) u16 As[128 * 32];
  __shared__ __align__(16) u16 Bs[128 * 32];
  const int tid = threadIdx.x;
  const int bm = blockIdx.y, bn = blockIdx.x;
  const int wv = tid >> 6, lane = tid & 63;
  const int wm = wv >> 1, wn = wv & 1;
  const int lr = lane & 15, lk = lane >> 4;

  // staging map: chunk id c (0..511) -> row c>>2, 16B-chunk c&3; source pre-swizzled
  const int srow = tid >> 2;
  const int scol = ((tid & 3) ^ ((tid >> 3) & 3)) * 8;
  const u16* Ag0 = A + (size_t)(bm * 128 + srow) * K + scol;
  const u16* Ag1 = Ag0 + (size_t)64 * K;
  const u16* Bg0 = Bt + (size_t)(bn * 128 + srow) * K + scol;
  const u16* Bg1 = Bg0 + (size_t)64 * K;
  u16* lA0 = As + wv * 512;          // wave-uniform LDS bases
  u16* lA1 = As + 2048 + wv * 512;
  u16* lB0 = Bs + wv * 512;
  u16* lB1 = Bs + 2048 + wv * 512;

  f32x4 acc[4][4];
  #pragma unroll
  for (int i = 0; i < 4; i++)
    #pragma unroll
    for (int j = 0; j < 4; j++) { acc[i][j][0]=0.f; acc[i][j][1]=0.f; acc[i][j][2]=0.f; acc[i][j][3]=0.f; }

  const int swz = (lr >> 1) & 3;     // read-side swizzle (matches source pre-swizzle)
  for (int k0 = 0; k0 < K; k0 += 32) {
    gload_lds16(Ag0 + k0, lA0);
    gload_lds16(Ag1 + k0, lA1);
    gload_lds16(Bg0 + k0, lB0);
    gload_lds16(Bg1 + k0, lB1);
    __syncthreads();
    bf16x8 af[4], bfr[4];
    #pragma unroll
    for (int f = 0; f < 4; f++) {
      af[f]  = *(const bf16x8*)&As[(wm * 64 + f * 16 + lr) * 32 + ((lk ^ swz) * 8)];
      bfr[f] = *(const bf16x8*)&Bs[(wn * 64 + f * 16 + lr) * 32 + ((lk ^ swz) * 8)];
    }
    #pragma unroll
    for (int fm = 0; fm < 4; fm++)
      #pragma unroll
      for (int fn = 0; fn < 4; fn++)
        acc[fm][fn] = __builtin_amdgcn_mfma_f32_16x16x32_bf16(af[fm], bfr[fn], acc[fm][fn], 0, 0, 0);
    __syncthreads();
  }

  const int rbase = bm * 128 + wm * 64;
  const int cbase = bn * 128 + wn * 64;
  #pragma unroll
  for (int fn = 0; fn < 4; fn++) {
    int Cc = cbase + fn * 16 + lr;
    float bv = bias ? bias[Cc] : 0.f;
    #pragma unroll
    for (int fm = 0; fm < 4; fm++) {
      #pragma unroll
      for (int j = 0; j < 4; j++) {
        int R = rbase + fm * 16 + lk * 4 + j;
        float v = acc[fm][fn][j] + bv;
        if (MODE == 0) {
          ((u16*)outp)[(size_t)R * N + Cc] = f2bf(v);
        } else if (MODE == 1) {
          ((float*)outp)[(size_t)R * N + Cc] = v;
        } else if (MODE == 2) {
          ((float*)outp)[(size_t)R * N + Cc] += v;
        } else if (MODE == 3) {
          ((u16*)outp)[(size_t)R * N + Cc] = f2bf(gelu_tanh(v));
        } else {
          int orow = rowmap[R];
          ((float*)outp)[(size_t)orow * N + Cc] = v;
        }
      }
    }
  }
}

// ---------------------------------------------------------------- windowed attention with fused RoPE
// one block per (window, head); 64 tokens, head_dim 80 (K padded to 96)
__global__ __launch_bounds__(256, 2) void attn_k(
    const u16* __restrict__ qkv, u16* __restrict__ outO,
    const float* __restrict__ cosr, const float* __restrict__ sinr) {
  __shared__ u16 Qs[64 * 104];
  __shared__ u16 Ks[64 * 104];
  __shared__ u16 Vt[80 * 72];
  __shared__ u16 Ps[64 * 72];
  const int w = blockIdx.x, hd = blockIdx.y;
  const int tid = threadIdx.x;
  const u16* base = qkv + (size_t)w * 64 * 3840 + hd * 80;

  for (int idx = tid; idx < 64 * 96; idx += 256) {
    int r = idx / 96, c = idx - r * 96;
    u16 qv = 0, kv = 0;
    if (c < 80) {
      int tokg = w * 64 + r;
      float cc = cosr[(size_t)tokg * 80 + c], ss = sinr[(size_t)tokg * 80 + c];
      int cp = (c < 40) ? c + 40 : c - 40;
      float sgn = (c < 40) ? -1.f : 1.f;
      float q  = bf2f(base[(size_t)r * 3840 + c]);
      float qp = bf2f(base[(size_t)r * 3840 + cp]);
      float k  = bf2f(base[(size_t)r * 3840 + 1280 + c]);
      float kp = bf2f(base[(size_t)r * 3840 + 1280 + cp]);
      qv = f2bf(q * cc + sgn * qp * ss);
      kv = f2bf(k * cc + sgn * kp * ss);
    }
    Qs[r * 104 + c] = qv;
    Ks[r * 104 + c] = kv;
  }
  for (int idx = tid; idx < 80 * 64; idx += 256) {
    int d = idx >> 6, kt = idx & 63;
    Vt[d * 72 + kt] = base[(size_t)kt * 3840 + 2560 + d];
  }
  __syncthreads();

  const int lane = tid & 63, wv = tid >> 6;
  const int lr = lane & 15, lk = lane >> 4;
  const float sc = 0.11180339887498949f;  // 80^-0.5

  f32x4 sfrag[4];
  #pragma unroll
  for (int f = 0; f < 4; f++) { sfrag[f][0]=0.f; sfrag[f][1]=0.f; sfrag[f][2]=0.f; sfrag[f][3]=0.f; }
  bf16x8 aq[3];
  #pragma unroll
  for (int ks = 0; ks < 3; ks++) aq[ks] = *(const bf16x8*)&Qs[(wv * 16 + lr) * 104 + ks * 32 + lk * 8];
  #pragma unroll
  for (int fn = 0; fn < 4; fn++) {
    #pragma unroll
    for (int ks = 0; ks < 3; ks++) {
      bf16x8 bk = *(const bf16x8*)&Ks[(fn * 16 + lr) * 104 + ks * 32 + lk * 8];
      sfrag[fn] = __builtin_amdgcn_mfma_f32_16x16x32_bf16(aq[ks], bk, sfrag[fn], 0, 0, 0);
    }
  }

  float inv[4];
  #pragma unroll
  for (int j = 0; j < 4; j++) {
    float mx = -1e30f;
    #pragma unroll
    for (int fn = 0; fn < 4; fn++) mx = fmaxf(mx, sfrag[fn][j] * sc);
    #pragma unroll
    for (int d = 1; d < 16; d <<= 1) mx = fmaxf(mx, __shfl_xor(mx, d, 64));
    float sum = 0.f;
    #pragma unroll
    for (int fn = 0; fn < 4; fn++) {
      float e = __expf(sfrag[fn][j] * sc - mx);
      Ps[(wv * 16 + lk * 4 + j) * 72 + fn * 16 + lr] = f2bf(e);
      sum += e;
    }
    #pragma unroll
    for (int d = 1; d < 16; d <<= 1) sum += __shfl_xor(sum, d, 64);
    inv[j] = 1.0f / sum;
  }
  __syncthreads();

  bf16x8 ap[2];
  #pragma unroll
  for (int ks = 0; ks < 2; ks++) ap[ks] = *(const bf16x8*)&Ps[(wv * 16 + lr) * 72 + ks * 32 + lk * 8];
  f32x4 of[5];
  #pragma unroll
  for (int f = 0; f < 5; f++) { of[f][0]=0.f; of[f][1]=0.f; of[f][2]=0.f; of[f][3]=0.f; }
  #pragma unroll
  for (int fn2 = 0; fn2 < 5; fn2++) {
    #pragma unroll
    for (int ks = 0; ks < 2; ks++) {
      bf16x8 bv = *(const bf16x8*)&Vt[(fn2 * 16 + lr) * 72 + ks * 32 + lk * 8];
      of[fn2] = __builtin_amdgcn_mfma_f32_16x16x32_bf16(ap[ks], bv, of[fn2], 0, 0, 0);
    }
  }

  #pragma unroll
  for (int fn2 = 0; fn2 < 5; fn2++) {
    #pragma unroll
    for (int j = 0; j < 4; j++) {
      int q = wv * 16 + lk * 4 + j;
      int d = fn2 * 16 + lr;
      outO[((size_t)(w * 64 + q)) * 1280 + hd * 80 + d] = f2bf(of[fn2][j] * inv[j]);
    }
  }
}

// ---------------------------------------------------------------- silu(g)*u, in place into g
__global__ __launch_bounds__(256) void silumul_k(u16* __restrict__ g, const u16* __restrict__ u) {
  int t = blockIdx.x * 256 + threadIdx.x;          // NTOK*432 groups of 8
  if (t >= NTOK * 432) return;
  u16x8 gv = *(const u16x8*)(g + (size_t)t * 8);
  u16x8 uv = *(const u16x8*)(u + (size_t)t * 8);
  u16x8 o;
  #pragma unroll
  for (int e = 0; e < 8; e++) {
    float x = bf2f(gv[e]), y = bf2f(uv[e]);
    float s = x / (1.f + __expf(-x));
    o[e] = f2bf(s * y);
  }
  *(u16x8*)(g + (size_t)t * 8) = o;
}

// ---------------------------------------------------------------- host
extern "C" void kernel_launch(void* const* d_in, const int* in_sizes, int n_in,
                              void* d_out, int out_size, void* d_ws, size_t ws_size,
                              hipStream_t stream) {
  (void)in_sizes; (void)n_in; (void)out_size; (void)ws_size;
  const float* pv   = (const float*)d_in[0];
  const float* cosi = (const float*)d_in[1];
  const float* sini = (const float*)d_in[2];
  const int*   wi   = (const int*)d_in[3];
  const float* Wp   = (const float*)d_in[4];
  const float* n1w  = (const float*)d_in[5];
  const float* qkvw = (const float*)d_in[6];
  const float* qkvb = (const float*)d_in[7];
  const float* pw   = (const float*)d_in[8];
  const float* pb   = (const float*)d_in[9];
  const float* n2w  = (const float*)d_in[10];
  const float* gw   = (const float*)d_in[11];
  const float* gb   = (const float*)d_in[12];
  const float* uw   = (const float*)d_in[13];
  const float* ub   = (const float*)d_in[14];
  const float* dw   = (const float*)d_in[15];
  const float* db   = (const float*)d_in[16];
  const float* mnw  = (const float*)d_in[17];
  const float* ml1w = (const float*)d_in[18];
  const float* ml1b = (const float*)d_in[19];
  const float* ml2w = (const float*)d_in[20];
  const float* ml2b = (const float*)d_in[21];
  const float* dnw  = (const float*)d_in[22];
  const float* dl1w = (const float*)d_in[23];
  const float* dl1b = (const float*)d_in[24];
  const float* dl2w = (const float*)d_in[25];
  const float* dl2b = (const float*)d_in[26];
  float* outv = (float*)d_out;
  char* ws = (char*)d_ws;

  size_t off = 0;
  float* h    = (float*)(ws + off); off += (size_t)NTOK * HID_ * 4;      // 84MB
  float* cosr = (float*)(ws + off); off += (size_t)NTOK * 80 * 4;
  float* sinr = (float*)(ws + off); off += (size_t)NTOK * 80 * 4;
  u16*  xb    = (u16*)(ws + off);  off += (size_t)NTOK * HID_ * 2;       // 42MB
  u16*  bufA  = (u16*)(ws + off);  off += (size_t)NTOK * 3840 * 2;       // 126MB
  u16*  bufB  = (u16*)(ws + off);  off += (size_t)NTOK * INTER_ * 2;     // 113MB
  u16*  bufC  = (u16*)(ws + off);  off += (size_t)NTOK * HID_ * 2;       // 42MB
  u16*  Wt    = (u16*)(ws + off);  off += (size_t)BIGD * BIGD * 2;       // 52.5MB

  dim3 B256(256);
  #define TW(src, K_, N_) twt_k<<<dim3((N_) / 32, (K_) / 32), B256, 0, stream>>>((src), Wt, (K_), (N_))

  // gather pixel rows + cos/sin
  gather_pv_k<<<(NTOK * 384 + 255) / 256, B256, 0, stream>>>(pv, wi, bufA);
  gather_cs_k<<<(NTOK * 20 + 255) / 256, B256, 0, stream>>>(cosi, sini, wi, cosr, sinr);

  // h = pv_g @ W_patch   (f32 out)
  TW(Wp, 1536, HID_);
  gemm2_k<1><<<dim3(HID_ / 128, NTOK / 128), B256, 0, stream>>>(bufA, Wt, nullptr, h, nullptr, HID_, 1536);

  for (int i = 0; i < 6; i++) {
    // attn
    rmsnorm_k<<<NTOK, B256, 0, stream>>>(h, n1w + (size_t)i * HID_, xb, HID_);
    TW(qkvw + (size_t)i * HID_ * 3840, HID_, 3840);
    gemm2_k<0><<<dim3(3840 / 128, NTOK / 128), B256, 0, stream>>>(
        xb, Wt, qkvb + (size_t)i * 3840, bufA, nullptr, 3840, HID_);
    attn_k<<<dim3(256, 16), B256, 0, stream>>>(bufA, bufC, cosr, sinr);
    TW(pw + (size_t)i * HID_ * HID_, HID_, HID_);
    gemm2_k<2><<<dim3(HID_ / 128, NTOK / 128), B256, 0, stream>>>(
        bufC, Wt, pb + (size_t)i * HID_, h, nullptr, HID_, HID_);
    // mlp
    rmsnorm_k<<<NTOK, B256, 0, stream>>>(h, n2w + (size_t)i * HID_, xb, HID_);
    TW(gw + (size_t)i * HID_ * INTER_, HID_, INTER_);
    gemm2_k<0><<<dim3(INTER_ / 128, NTOK / 128), B256, 0, stream>>>(
        xb, Wt, gb + (size_t)i * INTER_, bufA, nullptr, INTER_, HID_);
    TW(uw + (size_t)i * HID_ * INTER_, HID_, INTER_);
    gemm2_k<0><<<dim3(INTER_ / 128, NTOK / 128), B256, 0, stream>>>(
        xb, Wt, ub + (size_t)i * INTER_, bufB, nullptr, INTER_, HID_);
    silumul_k<<<(NTOK * 432 + 255) / 256, B256, 0, stream>>>(bufA, bufB);
    TW(dw + (size_t)i * INTER_ * HID_, INTER_, HID_);
    gemm2_k<2><<<dim3(HID_ / 128, NTOK / 128), B256, 0, stream>>>(
        bufA, Wt, db + (size_t)i * HID_, h, nullptr, HID_, INTER_);
    // deepstack mergers after layers 2 and 4
    if (i == 2 || i == 4) {
      int j = (i == 2) ? 0 : 1;
      rmsnorm_k<<<NGRP, B256, 0, stream>>>(h, dnw + (size_t)j * BIGD, bufC, BIGD);
      TW(dl1w + (size_t)j * BIGD * BIGD, BIGD, BIGD);
      gemm2_k<3><<<dim3(BIGD / 128, NGRP / 128), B256, 0, stream>>>(
          bufC, Wt, dl1b + (size_t)j * BIGD, bufA, nullptr, BIGD, BIGD);
      TW(dl2w + (size_t)j * BIGD * ODIM, BIGD, ODIM);
      gemm2_k<4><<<dim3(ODIM / 128, NGRP / 128), B256, 0, stream>>>(
          bufA, Wt, dl2b + (size_t)j * ODIM, outv + (size_t)(1 + j) * NGRP * ODIM, wi, ODIM, BIGD);
    }
  }

  // final merger -> plane 0
  rmsnorm_k<<<NTOK, B256, 0, stream>>>(h, mnw, bufC, HID_);
  TW(ml1w, BIGD, BIGD);
  gemm2_k<3><<<dim3(BIGD / 128, NGRP / 128), B256, 0, stream>>>(
      bufC, Wt, ml1b, bufA, nullptr, BIGD, BIGD);
  TW(ml2w, BIGD, ODIM);
  gemm2_k<4><<<dim3(ODIM / 128, NGRP / 128), B256, 0, stream>>>(
      bufA, Wt, ml2b, outv, wi, ODIM, BIGD);
  #undef TW
}

// Round 5
// 9362.679 us; speedup vs baseline: 1.5817x; 1.1055x over previous
//
#include <hip/hip_runtime.h>
#include <hip/hip_bf16.h>

typedef unsigned short u16;
typedef __bf16 bf16x8 __attribute__((ext_vector_type(8)));
typedef float   f32x4 __attribute__((ext_vector_type(4)));
typedef unsigned short u16x8 __attribute__((ext_vector_type(8)));

#define NTOK  16384
#define HID_  1280
#define NHEAD 16
#define HD    80
#define INTER_ 3456
#define NGRP  4096
#define ODIM  2048
#define BIGD  5120

static __device__ __forceinline__ u16 f2bf(float f) {
  __hip_bfloat16 h = __float2bfloat16(f);
  return __builtin_bit_cast(u16, h);
}
static __device__ __forceinline__ float bf2f(u16 u) {
  return __bfloat162float(__builtin_bit_cast(__hip_bfloat16, u));
}
static __device__ __forceinline__ float gelu_tanh(float x) {
  float x3 = x * x * x;
  return 0.5f * x * (1.0f + tanhf(0.7978845608028654f * (x + 0.044715f * x3)));
}

// async global->LDS, 16B per lane, dest = wave-uniform base + lane*16
static __device__ __forceinline__ void gload_lds16(const u16* g, u16* l) {
  __builtin_amdgcn_global_load_lds(
      (const __attribute__((address_space(1))) unsigned int*)g,
      (__attribute__((address_space(3))) unsigned int*)l, 16, 0, 0);
}

// ---------------------------------------------------------------- gathers
__global__ __launch_bounds__(256) void gather_pv_k(
    const float* __restrict__ pv, const int* __restrict__ wi, u16* __restrict__ out) {
  int t = blockIdx.x * 256 + threadIdx.x;          // NTOK*384 float4 groups
  if (t >= NTOK * 384) return;
  int i = t / 384, c4 = t - i * 384;
  int s = wi[i >> 2] * 4 + (i & 3);
  float4 v = *(const float4*)(pv + (size_t)s * 1536 + c4 * 4);
  uint2 r;
  r.x = (unsigned)f2bf(v.x) | ((unsigned)f2bf(v.y) << 16);
  r.y = (unsigned)f2bf(v.z) | ((unsigned)f2bf(v.w) << 16);
  *(uint2*)(out + (size_t)i * 1536 + c4 * 4) = r;
}

__global__ __launch_bounds__(256) void gather_cs_k(
    const float* __restrict__ ci, const float* __restrict__ si,
    const int* __restrict__ wi, float* __restrict__ co, float* __restrict__ so) {
  int t = blockIdx.x * 256 + threadIdx.x;          // NTOK*20 float4 groups
  if (t >= NTOK * 20) return;
  int i = t / 20, c4 = t - i * 20;
  int s = wi[i >> 2] * 4 + (i & 3);
  *(float4*)(co + (size_t)i * 80 + c4 * 4) = *(const float4*)(ci + (size_t)s * 80 + c4 * 4);
  *(float4*)(so + (size_t)i * 80 + c4 * 4) = *(const float4*)(si + (size_t)s * 80 + c4 * 4);
}

// ---------------------------------------------------------------- weight f32[K][N] -> bf16[N][K]
__global__ __launch_bounds__(256) void twt_k(
    const float* __restrict__ W, u16* __restrict__ Wt, int K, int N) {
  __shared__ u16 t[32][33];
  int bn = blockIdx.x * 32, bk = blockIdx.y * 32;
  int tx = threadIdx.x & 31, ty = threadIdx.x >> 5;   // ty 0..7
  #pragma unroll
  for (int r = 0; r < 4; r++) {
    int k = bk + ty + r * 8;
    t[tx][ty + r * 8] = f2bf(W[(size_t)k * N + bn + tx]);
  }
  __syncthreads();
  #pragma unroll
  for (int r = 0; r < 4; r++) {
    int n = bn + ty + r * 8;
    Wt[(size_t)n * K + bk + tx] = t[ty + r * 8][tx];
  }
}

// ---------------------------------------------------------------- rmsnorm (f32 in -> bf16 out)
__global__ __launch_bounds__(256) void rmsnorm_k(
    const float* __restrict__ x, const float* __restrict__ w, u16* __restrict__ out, int D) {
  int row = blockIdx.x;
  const float* xr = x + (size_t)row * D;
  float ss = 0.f;
  for (int c = threadIdx.x; c < D; c += 256) { float v = xr[c]; ss += v * v; }
  #pragma unroll
  for (int d = 1; d < 64; d <<= 1) ss += __shfl_xor(ss, d, 64);
  __shared__ float part[4];
  if ((threadIdx.x & 63) == 0) part[threadIdx.x >> 6] = ss;
  __syncthreads();
  float tot = part[0] + part[1] + part[2] + part[3];
  float scale = rsqrtf(tot / (float)D + 1e-6f);
  u16* orow = out + (size_t)row * D;
  for (int c = threadIdx.x; c < D; c += 256) orow[c] = f2bf(xr[c] * scale * w[c]);
}

// ---------------------------------------------------------------- 128^2 GEMM (kept for small-N merger L2)
// MODE 4: f32 scatter rows via rowmap
template <int MODE>
__global__ __launch_bounds__(256, 2) void gemm2_k(
    const u16* __restrict__ A, const u16* __restrict__ Bt, const float* __restrict__ bias,
    void* __restrict__ outp, const int* __restrict__ rowmap, int N, int K) {
  __shared__ __align__(16) u16 As[128 * 32];
  __shared__ __align__(16) u16 Bs[128 * 32];
  const int tid = threadIdx.x;
  const int bm = blockIdx.y, bn = blockIdx.x;
  const int wv = tid >> 6, lane = tid & 63;
  const int wm = wv >> 1, wn = wv & 1;
  const int lr = lane & 15, lk = lane >> 4;

  const int srow = tid >> 2;
  const int scol = ((tid & 3) ^ ((tid >> 3) & 3)) * 8;
  const u16* Ag0 = A + (size_t)(bm * 128 + srow) * K + scol;
  const u16* Ag1 = Ag0 + (size_t)64 * K;
  const u16* Bg0 = Bt + (size_t)(bn * 128 + srow) * K + scol;
  const u16* Bg1 = Bg0 + (size_t)64 * K;
  u16* lA0 = As + wv * 512;
  u16* lA1 = As + 2048 + wv * 512;
  u16* lB0 = Bs + wv * 512;
  u16* lB1 = Bs + 2048 + wv * 512;

  f32x4 acc[4][4];
  #pragma unroll
  for (int i = 0; i < 4; i++)
    #pragma unroll
    for (int j = 0; j < 4; j++) { acc[i][j][0]=0.f; acc[i][j][1]=0.f; acc[i][j][2]=0.f; acc[i][j][3]=0.f; }

  const int swz = (lr >> 1) & 3;
  for (int k0 = 0; k0 < K; k0 += 32) {
    gload_lds16(Ag0 + k0, lA0);
    gload_lds16(Ag1 + k0, lA1);
    gload_lds16(Bg0 + k0, lB0);
    gload_lds16(Bg1 + k0, lB1);
    __syncthreads();
    bf16x8 af[4], bfr[4];
    #pragma unroll
    for (int f = 0; f < 4; f++) {
      af[f]  = *(const bf16x8*)&As[(wm * 64 + f * 16 + lr) * 32 + ((lk ^ swz) * 8)];
      bfr[f] = *(const bf16x8*)&Bs[(wn * 64 + f * 16 + lr) * 32 + ((lk ^ swz) * 8)];
    }
    #pragma unroll
    for (int fm = 0; fm < 4; fm++)
      #pragma unroll
      for (int fn = 0; fn < 4; fn++)
        acc[fm][fn] = __builtin_amdgcn_mfma_f32_16x16x32_bf16(af[fm], bfr[fn], acc[fm][fn], 0, 0, 0);
    __syncthreads();
  }

  const int rbase = bm * 128 + wm * 64;
  const int cbase = bn * 128 + wn * 64;
  #pragma unroll
  for (int fn = 0; fn < 4; fn++) {
    int Cc = cbase + fn * 16 + lr;
    float bv = bias ? bias[Cc] : 0.f;
    #pragma unroll
    for (int fm = 0; fm < 4; fm++) {
      #pragma unroll
      for (int j = 0; j < 4; j++) {
        int R = rbase + fm * 16 + lk * 4 + j;
        float v = acc[fm][fn][j] + bv;
        if (MODE == 4) {
          int orow = rowmap[R];
          ((float*)outp)[(size_t)orow * N + Cc] = v;
        } else {
          ((float*)outp)[(size_t)R * N + Cc] = v;
        }
      }
    }
  }
}

// ---------------------------------------------------------------- 256^2 8-phase GEMM (T2+T3+T4+T5)
// C = A(bf16 [M][K]) @ Bt(bf16 [N][K])^T + bias. 512 threads, 8 waves (2M x 4N).
// LDS: 2 bufs x (A[256][64] + B[256][64]) bf16, XOR-swizzled 16B chunks:
//   LDS[r][c] = G[r][c ^ (r&7)] (c = 16B chunk 0..7), staged via linear
//   gload_lds dest + pre-swizzled global source; reads re-apply the XOR.
// Stage order per phase p: [A0,B0,A1,B1] of tile t+1; quadrants:
//   p0: A1xB1 of tile t-1; p1: A0xB0; p2: A1xB0; p3: A0xB1 (of tile t).
// vmcnt(6) per phase = 3 half-tile stage-events in flight across barriers.
// MODE 0: bf16 store; 1: f32; 2: f32 +=; 3: gelu->bf16
template <int MODE>
__global__ __launch_bounds__(512, 2) void gemm8_k(
    const u16* __restrict__ A, const u16* __restrict__ Bt, const float* __restrict__ bias,
    void* __restrict__ outp, int N, int K) {
  __shared__ __align__(16) u16 LDS[65536];   // 128 KiB
  const int tid = threadIdx.x;
  const int w = tid >> 6, lane = tid & 63;
  const int wm = w >> 2, wn = w & 3;
  const int lr = lane & 15, lk = lane >> 4, lrm = lr & 7;
  const int bn = blockIdx.x, bm = blockIdx.y;
  const int NT = K >> 6;
  const size_t Kb = (size_t)K * 2;
  const int l8 = lane >> 3, l7 = lane & 7;
  const int schunk = l7 ^ l8;                 // pre-swizzled source chunk

  const unsigned wm16lr = (unsigned)(wm * 16 + lr) * 128u;
  const unsigned wn16lr = (unsigned)(wn * 16 + lr) * 128u;
  unsigned ch[2];
  ch[0] = (unsigned)(((lk) ^ lrm) << 4);
  ch[1] = (unsigned)(((4 + lk) ^ lrm) << 4);
  const char* LB = (const char*)&LDS[0];

  f32x4 acc[8][4];
  #pragma unroll
  for (int f = 0; f < 8; f++)
    #pragma unroll
    for (int n = 0; n < 4; n++) { acc[f][n][0]=0.f; acc[f][n][1]=0.f; acc[f][n][2]=0.f; acc[f][n][3]=0.f; }

  const char* Ab = (const char*)A;
  const char* Bb = (const char*)Bt;
  u16* LDSp = &LDS[0];

  // stage one half-tile (2 x gload_lds per wave). isB: operand; half: 0/1; tt: K-tile; bb: lds buf
  auto STAGE = [&](int isB, int half, int tt, int bb) {
    long k0b = (long)tt * 128;
    const char* base = isB ? Bb : Ab;
    int rb = (isB ? bn : bm) * 256 + half * 128;
    #pragma unroll
    for (int i = 0; i < 2; i++) {
      int r0 = half * 128 + i * 64 + w * 8;          // LDS row in tile (wave-uniform)
      int gr = rb + i * 64 + w * 8 + l8;             // global row (per-lane)
      if (isB && gr >= N) gr = N - 1;
      const char* src = base + (size_t)gr * Kb + k0b + schunk * 16;
      unsigned dst = (isB ? 65536u : 0u) + (unsigned)bb * 32768u + (unsigned)r0 * 128u;
      gload_lds16((const u16*)src, LDSp + dst / 2);
    }
  };

#define QREAD(FA, NB, BUFOFF)                                                       \
    _Pragma("unroll") for (int f = 0; f < 4; f++) {                                 \
      _Pragma("unroll") for (int kk = 0; kk < 2; kk++) {                            \
        unsigned ad = (BUFOFF) + (unsigned)((FA) + f) * 4096u + wm16lr + ch[kk];    \
        af[f][kk] = *(const bf16x8*)(LB + ad);                                      \
      }                                                                             \
    }                                                                               \
    _Pragma("unroll") for (int n = 0; n < 2; n++) {                                 \
      _Pragma("unroll") for (int kk = 0; kk < 2; kk++) {                            \
        unsigned ad = 65536u + (BUFOFF) + (unsigned)((NB) + n) * 8192u + wn16lr + ch[kk]; \
        bfr[n][kk] = *(const bf16x8*)(LB + ad);                                     \
      }                                                                             \
    }

#define QMFMA(FA, NB)                                                               \
    __builtin_amdgcn_s_setprio(1);                                                  \
    _Pragma("unroll") for (int kk = 0; kk < 2; kk++) {                              \
      _Pragma("unroll") for (int f = 0; f < 4; f++) {                               \
        _Pragma("unroll") for (int n = 0; n < 2; n++) {                             \
          acc[(FA) + f][(NB) + n] = __builtin_amdgcn_mfma_f32_16x16x32_bf16(        \
              af[f][kk], bfr[n][kk], acc[(FA) + f][(NB) + n], 0, 0, 0);             \
        }                                                                           \
      }                                                                             \
    }                                                                               \
    __builtin_amdgcn_s_setprio(0);

#define SYNC1                                                                       \
    asm volatile("s_waitcnt vmcnt(6)" ::: "memory");                                \
    __builtin_amdgcn_s_barrier();                                                   \
    asm volatile("s_waitcnt lgkmcnt(0)" ::: "memory");                              \
    __builtin_amdgcn_sched_barrier(0);

#define SYNC2                                                                       \
    __builtin_amdgcn_s_barrier();                                                   \
    __builtin_amdgcn_sched_barrier(0);

  // prologue: stage tile 0 fully into buf 0 (events -4..-1)
  STAGE(0, 0, 0, 0);
  STAGE(1, 0, 0, 0);
  STAGE(0, 1, 0, 0);
  STAGE(1, 1, 0, 0);

  for (int t = 0; t < NT; t++) {
    const unsigned bo  = (unsigned)(t & 1) * 32768u;   // current tile buf
    const unsigned bop = bo ^ 32768u;                  // prev-tile / next-tile buf
    const int bb1 = (t + 1) & 1;
    const int tn = (t + 1 < NT) ? (t + 1) : 0;         // clamp dummy stage source
    // ---- phase 0: quadrant A1xB1 of tile t-1
    {
      bf16x8 af[4][2], bfr[2][2];
      if (t > 0) { QREAD(4, 2, bop) }
      STAGE(0, 0, tn, bb1);
      SYNC1
      if (t > 0) { QMFMA(4, 2) }
      SYNC2
    }
    // ---- phase 1: A0xB0 of tile t
    {
      bf16x8 af[4][2], bfr[2][2];
      QREAD(0, 0, bo)
      STAGE(1, 0, tn, bb1);
      SYNC1
      QMFMA(0, 0)
      SYNC2
    }
    // ---- phase 2: A1xB0
    {
      bf16x8 af[4][2], bfr[2][2];
      QREAD(4, 0, bo)
      STAGE(0, 1, tn, bb1);
      SYNC1
      QMFMA(4, 0)
      SYNC2
    }
    // ---- phase 3: A0xB1
    {
      bf16x8 af[4][2], bfr[2][2];
      QREAD(0, 2, bo)
      STAGE(1, 1, tn, bb1);
      SYNC1
      QMFMA(0, 2)
      SYNC2
    }
  }
  // tail: A1xB1 of tile NT-1 (its halves staged >=4 events ago; buf parity (NT-1)&1)
  {
    bf16x8 af[4][2], bfr[2][2];
    const unsigned bo = (unsigned)((NT - 1) & 1) * 32768u;
    QREAD(4, 2, bo)
    asm volatile("s_waitcnt lgkmcnt(0)" ::: "memory");
    __builtin_amdgcn_sched_barrier(0);
    QMFMA(4, 2)
  }
#undef QREAD
#undef QMFMA
#undef SYNC1
#undef SYNC2

  // epilogue
  #pragma unroll
  for (int n = 0; n < 4; n++) {
    int Cc = bn * 256 + n * 64 + wn * 16 + lr;
    bool ok = (Cc < N);
    float bv = (bias && ok) ? bias[Cc] : 0.f;
    #pragma unroll
    for (int f = 0; f < 8; f++) {
      #pragma unroll
      for (int j = 0; j < 4; j++) {
        int R = bm * 256 + f * 32 + wm * 16 + lk * 4 + j;
        float v = acc[f][n][j] + bv;
        if (ok) {
          if (MODE == 0) {
            ((u16*)outp)[(size_t)R * N + Cc] = f2bf(v);
          } else if (MODE == 1) {
            ((float*)outp)[(size_t)R * N + Cc] = v;
          } else if (MODE == 2) {
            ((float*)outp)[(size_t)R * N + Cc] += v;
          } else {
            ((u16*)outp)[(size_t)R * N + Cc] = f2bf(gelu_tanh(v));
          }
        }
      }
    }
  }
}

// ---------------------------------------------------------------- windowed attention with fused RoPE
__global__ __launch_bounds__(256, 2) void attn_k(
    const u16* __restrict__ qkv, u16* __restrict__ outO,
    const float* __restrict__ cosr, const float* __restrict__ sinr) {
  __shared__ u16 Qs[64 * 104];
  __shared__ u16 Ks[64 * 104];
  __shared__ u16 Vt[80 * 72];
  __shared__ u16 Ps[64 * 72];
  const int w = blockIdx.x, hd = blockIdx.y;
  const int tid = threadIdx.x;
  const u16* base = qkv + (size_t)w * 64 * 3840 + hd * 80;

  for (int idx = tid; idx < 64 * 96; idx += 256) {
    int r = idx / 96, c = idx - r * 96;
    u16 qv = 0, kv = 0;
    if (c < 80) {
      int tokg = w * 64 + r;
      float cc = cosr[(size_t)tokg * 80 + c], ss = sinr[(size_t)tokg * 80 + c];
      int cp = (c < 40) ? c + 40 : c - 40;
      float sgn = (c < 40) ? -1.f : 1.f;
      float q  = bf2f(base[(size_t)r * 3840 + c]);
      float qp = bf2f(base[(size_t)r * 3840 + cp]);
      float k  = bf2f(base[(size_t)r * 3840 + 1280 + c]);
      float kp = bf2f(base[(size_t)r * 3840 + 1280 + cp]);
      qv = f2bf(q * cc + sgn * qp * ss);
      kv = f2bf(k * cc + sgn * kp * ss);
    }
    Qs[r * 104 + c] = qv;
    Ks[r * 104 + c] = kv;
  }
  for (int idx = tid; idx < 80 * 64; idx += 256) {
    int d = idx >> 6, kt = idx & 63;
    Vt[d * 72 + kt] = base[(size_t)kt * 3840 + 2560 + d];
  }
  __syncthreads();

  const int lane = tid & 63, wv = tid >> 6;
  const int lr = lane & 15, lk = lane >> 4;
  const float sc = 0.11180339887498949f;  // 80^-0.5

  f32x4 sfrag[4];
  #pragma unroll
  for (int f = 0; f < 4; f++) { sfrag[f][0]=0.f; sfrag[f][1]=0.f; sfrag[f][2]=0.f; sfrag[f][3]=0.f; }
  bf16x8 aq[3];
  #pragma unroll
  for (int ks = 0; ks < 3; ks++) aq[ks] = *(const bf16x8*)&Qs[(wv * 16 + lr) * 104 + ks * 32 + lk * 8];
  #pragma unroll
  for (int fn = 0; fn < 4; fn++) {
    #pragma unroll
    for (int ks = 0; ks < 3; ks++) {
      bf16x8 bk = *(const bf16x8*)&Ks[(fn * 16 + lr) * 104 + ks * 32 + lk * 8];
      sfrag[fn] = __builtin_amdgcn_mfma_f32_16x16x32_bf16(aq[ks], bk, sfrag[fn], 0, 0, 0);
    }
  }

  float inv[4];
  #pragma unroll
  for (int j = 0; j < 4; j++) {
    float mx = -1e30f;
    #pragma unroll
    for (int fn = 0; fn < 4; fn++) mx = fmaxf(mx, sfrag[fn][j] * sc);
    #pragma unroll
    for (int d = 1; d < 16; d <<= 1) mx = fmaxf(mx, __shfl_xor(mx, d, 64));
    float sum = 0.f;
    #pragma unroll
    for (int fn = 0; fn < 4; fn++) {
      float e = __expf(sfrag[fn][j] * sc - mx);
      Ps[(wv * 16 + lk * 4 + j) * 72 + fn * 16 + lr] = f2bf(e);
      sum += e;
    }
    #pragma unroll
    for (int d = 1; d < 16; d <<= 1) sum += __shfl_xor(sum, d, 64);
    inv[j] = 1.0f / sum;
  }
  __syncthreads();

  bf16x8 ap[2];
  #pragma unroll
  for (int ks = 0; ks < 2; ks++) ap[ks] = *(const bf16x8*)&Ps[(wv * 16 + lr) * 72 + ks * 32 + lk * 8];
  f32x4 of[5];
  #pragma unroll
  for (int f = 0; f < 5; f++) { of[f][0]=0.f; of[f][1]=0.f; of[f][2]=0.f; of[f][3]=0.f; }
  #pragma unroll
  for (int fn2 = 0; fn2 < 5; fn2++) {
    #pragma unroll
    for (int ks = 0; ks < 2; ks++) {
      bf16x8 bv = *(const bf16x8*)&Vt[(fn2 * 16 + lr) * 72 + ks * 32 + lk * 8];
      of[fn2] = __builtin_amdgcn_mfma_f32_16x16x32_bf16(ap[ks], bv, of[fn2], 0, 0, 0);
    }
  }

  #pragma unroll
  for (int fn2 = 0; fn2 < 5; fn2++) {
    #pragma unroll
    for (int j = 0; j < 4; j++) {
      int q = wv * 16 + lk * 4 + j;
      int d = fn2 * 16 + lr;
      outO[((size_t)(w * 64 + q)) * 1280 + hd * 80 + d] = f2bf(of[fn2][j] * inv[j]);
    }
  }
}

// ---------------------------------------------------------------- silu(g)*u, in place into g
__global__ __launch_bounds__(256) void silumul_k(u16* __restrict__ g, const u16* __restrict__ u) {
  int t = blockIdx.x * 256 + threadIdx.x;          // NTOK*432 groups of 8
  if (t >= NTOK * 432) return;
  u16x8 gv = *(const u16x8*)(g + (size_t)t * 8);
  u16x8 uv = *(const u16x8*)(u + (size_t)t * 8);
  u16x8 o;
  #pragma unroll
  for (int e = 0; e < 8; e++) {
    float x = bf2f(gv[e]), y = bf2f(uv[e]);
    float s = x / (1.f + __expf(-x));
    o[e] = f2bf(s * y);
  }
  *(u16x8*)(g + (size_t)t * 8) = o;
}

// ---------------------------------------------------------------- host
extern "C" void kernel_launch(void* const* d_in, const int* in_sizes, int n_in,
                              void* d_out, int out_size, void* d_ws, size_t ws_size,
                              hipStream_t stream) {
  (void)in_sizes; (void)n_in; (void)out_size; (void)ws_size;
  const float* pv   = (const float*)d_in[0];
  const float* cosi = (const float*)d_in[1];
  const float* sini = (const float*)d_in[2];
  const int*   wi   = (const int*)d_in[3];
  const float* Wp   = (const float*)d_in[4];
  const float* n1w  = (const float*)d_in[5];
  const float* qkvw = (const float*)d_in[6];
  const float* qkvb = (const float*)d_in[7];
  const float* pw   = (const float*)d_in[8];
  const float* pb   = (const float*)d_in[9];
  const float* n2w  = (const float*)d_in[10];
  const float* gw   = (const float*)d_in[11];
  const float* gb   = (const float*)d_in[12];
  const float* uw   = (const float*)d_in[13];
  const float* ub   = (const float*)d_in[14];
  const float* dw   = (const float*)d_in[15];
  const float* db   = (const float*)d_in[16];
  const float* mnw  = (const float*)d_in[17];
  const float* ml1w = (const float*)d_in[18];
  const float* ml1b = (const float*)d_in[19];
  const float* ml2w = (const float*)d_in[20];
  const float* ml2b = (const float*)d_in[21];
  const float* dnw  = (const float*)d_in[22];
  const float* dl1w = (const float*)d_in[23];
  const float* dl1b = (const float*)d_in[24];
  const float* dl2w = (const float*)d_in[25];
  const float* dl2b = (const float*)d_in[26];
  float* outv = (float*)d_out;
  char* ws = (char*)d_ws;

  size_t off = 0;
  float* h    = (float*)(ws + off); off += (size_t)NTOK * HID_ * 4;      // 84MB
  float* cosr = (float*)(ws + off); off += (size_t)NTOK * 80 * 4;
  float* sinr = (float*)(ws + off); off += (size_t)NTOK * 80 * 4;
  u16*  xb    = (u16*)(ws + off);  off += (size_t)NTOK * HID_ * 2;       // 42MB
  u16*  bufA  = (u16*)(ws + off);  off += (size_t)NTOK * 3840 * 2;       // 126MB
  u16*  bufB  = (u16*)(ws + off);  off += (size_t)NTOK * INTER_ * 2;     // 113MB
  u16*  bufC  = (u16*)(ws + off);  off += (size_t)NTOK * HID_ * 2;       // 42MB
  u16*  Wt    = (u16*)(ws + off);  off += (size_t)BIGD * BIGD * 2;       // 52.5MB

  dim3 B256(256), B512(512);
  #define TW(src, K_, N_) twt_k<<<dim3((N_) / 32, (K_) / 32), B256, 0, stream>>>((src), Wt, (K_), (N_))
  #define G8(MODE, Abuf, bias_, out_, M_, N_, K_)                                         \
    gemm8_k<MODE><<<dim3(((N_) + 255) / 256, (M_) / 256), B512, 0, stream>>>(             \
        (Abuf), Wt, (bias_), (out_), (N_), (K_))

  // gather pixel rows + cos/sin
  gather_pv_k<<<(NTOK * 384 + 255) / 256, B256, 0, stream>>>(pv, wi, bufA);
  gather_cs_k<<<(NTOK * 20 + 255) / 256, B256, 0, stream>>>(cosi, sini, wi, cosr, sinr);

  // h = pv_g @ W_patch   (f32 out)
  TW(Wp, 1536, HID_);
  G8(1, bufA, nullptr, h, NTOK, HID_, 1536);

  for (int i = 0; i < 6; i++) {
    // attn
    rmsnorm_k<<<NTOK, B256, 0, stream>>>(h, n1w + (size_t)i * HID_, xb, HID_);
    TW(qkvw + (size_t)i * HID_ * 3840, HID_, 3840);
    G8(0, xb, qkvb + (size_t)i * 3840, bufA, NTOK, 3840, HID_);
    attn_k<<<dim3(256, 16), B256, 0, stream>>>(bufA, bufC, cosr, sinr);
    TW(pw + (size_t)i * HID_ * HID_, HID_, HID_);
    G8(2, bufC, pb + (size_t)i * HID_, h, NTOK, HID_, HID_);
    // mlp
    rmsnorm_k<<<NTOK, B256, 0, stream>>>(h, n2w + (size_t)i * HID_, xb, HID_);
    TW(gw + (size_t)i * HID_ * INTER_, HID_, INTER_);
    G8(0, xb, gb + (size_t)i * INTER_, bufA, NTOK, INTER_, HID_);
    TW(uw + (size_t)i * HID_ * INTER_, HID_, INTER_);
    G8(0, xb, ub + (size_t)i * INTER_, bufB, NTOK, INTER_, HID_);
    silumul_k<<<(NTOK * 432 + 255) / 256, B256, 0, stream>>>(bufA, bufB);
    TW(dw + (size_t)i * INTER_ * HID_, INTER_, HID_);
    G8(2, bufA, db + (size_t)i * HID_, h, NTOK, HID_, INTER_);
    // deepstack mergers after layers 2 and 4
    if (i == 2 || i == 4) {
      int j = (i == 2) ? 0 : 1;
      rmsnorm_k<<<NGRP, B256, 0, stream>>>(h, dnw + (size_t)j * BIGD, bufC, BIGD);
      TW(dl1w + (size_t)j * BIGD * BIGD, BIGD, BIGD);
      G8(3, bufC, dl1b + (size_t)j * BIGD, bufA, NGRP, BIGD, BIGD);
      TW(dl2w + (size_t)j * BIGD * ODIM, BIGD, ODIM);
      gemm2_k<4><<<dim3(ODIM / 128, NGRP / 128), B256, 0, stream>>>(
          bufA, Wt, dl2b + (size_t)j * ODIM, outv + (size_t)(1 + j) * NGRP * ODIM, wi, ODIM, BIGD);
    }
  }

  // final merger -> plane 0
  rmsnorm_k<<<NTOK, B256, 0, stream>>>(h, mnw, bufC, HID_);
  TW(ml1w, BIGD, BIGD);
  G8(3, bufC, ml1b, bufA, NGRP, BIGD, BIGD);
  TW(ml2w, BIGD, ODIM);
  gemm2_k<4><<<dim3(ODIM / 128, NGRP / 128), B256, 0, stream>>>(
      bufA, Wt, ml2b, outv, wi, ODIM, BIGD);
  #undef TW
  #undef G8
}

// Round 6
// 9033.555 us; speedup vs baseline: 1.6393x; 1.0364x over previous
//
#include <hip/hip_runtime.h>
#include <hip/hip_bf16.h>

typedef unsigned short u16;
typedef __bf16 bf16x8 __attribute__((ext_vector_type(8)));
typedef float   f32x4 __attribute__((ext_vector_type(4)));
typedef unsigned short u16x8 __attribute__((ext_vector_type(8)));

#define NTOK  16384
#define HID_  1280
#define NHEAD 16
#define HD    80
#define INTER_ 3456
#define NGRP  4096
#define ODIM  2048
#define BIGD  5120

static __device__ __forceinline__ u16 f2bf(float f) {
  __hip_bfloat16 h = __float2bfloat16(f);
  return __builtin_bit_cast(u16, h);
}
static __device__ __forceinline__ float bf2f(u16 u) {
  return __bfloat162float(__builtin_bit_cast(__hip_bfloat16, u));
}
static __device__ __forceinline__ float gelu_tanh(float x) {
  float x3 = x * x * x;
  return 0.5f * x * (1.0f + tanhf(0.7978845608028654f * (x + 0.044715f * x3)));
}

// async global->LDS, 16B per lane, dest = wave-uniform base + lane*16
static __device__ __forceinline__ void gload_lds16(const u16* g, u16* l) {
  __builtin_amdgcn_global_load_lds(
      (const __attribute__((address_space(1))) unsigned int*)g,
      (__attribute__((address_space(3))) unsigned int*)l, 16, 0, 0);
}

// ---------------------------------------------------------------- gathers
__global__ __launch_bounds__(256) void gather_pv_k(
    const float* __restrict__ pv, const int* __restrict__ wi, u16* __restrict__ out) {
  int t = blockIdx.x * 256 + threadIdx.x;          // NTOK*384 float4 groups
  if (t >= NTOK * 384) return;
  int i = t / 384, c4 = t - i * 384;
  int s = wi[i >> 2] * 4 + (i & 3);
  float4 v = *(const float4*)(pv + (size_t)s * 1536 + c4 * 4);
  uint2 r;
  r.x = (unsigned)f2bf(v.x) | ((unsigned)f2bf(v.y) << 16);
  r.y = (unsigned)f2bf(v.z) | ((unsigned)f2bf(v.w) << 16);
  *(uint2*)(out + (size_t)i * 1536 + c4 * 4) = r;
}

__global__ __launch_bounds__(256) void gather_cs_k(
    const float* __restrict__ ci, const float* __restrict__ si,
    const int* __restrict__ wi, float* __restrict__ co, float* __restrict__ so) {
  int t = blockIdx.x * 256 + threadIdx.x;          // NTOK*20 float4 groups
  if (t >= NTOK * 20) return;
  int i = t / 20, c4 = t - i * 20;
  int s = wi[i >> 2] * 4 + (i & 3);
  *(float4*)(co + (size_t)i * 80 + c4 * 4) = *(const float4*)(ci + (size_t)s * 80 + c4 * 4);
  *(float4*)(so + (size_t)i * 80 + c4 * 4) = *(const float4*)(si + (size_t)s * 80 + c4 * 4);
}

// ---------------------------------------------------------------- weight f32[K][N] -> bf16[N][K]
__global__ __launch_bounds__(256) void twt_k(
    const float* __restrict__ W, u16* __restrict__ Wt, int K, int N) {
  __shared__ u16 t[32][33];
  int bn = blockIdx.x * 32, bk = blockIdx.y * 32;
  int tx = threadIdx.x & 31, ty = threadIdx.x >> 5;   // ty 0..7
  #pragma unroll
  for (int r = 0; r < 4; r++) {
    int k = bk + ty + r * 8;
    t[tx][ty + r * 8] = f2bf(W[(size_t)k * N + bn + tx]);
  }
  __syncthreads();
  #pragma unroll
  for (int r = 0; r < 4; r++) {
    int n = bn + ty + r * 8;
    Wt[(size_t)n * K + bk + tx] = t[ty + r * 8][tx];
  }
}

// ---------------------------------------------------------------- rmsnorm (f32 in -> bf16 out)
__global__ __launch_bounds__(256) void rmsnorm_k(
    const float* __restrict__ x, const float* __restrict__ w, u16* __restrict__ out, int D) {
  int row = blockIdx.x;
  const float* xr = x + (size_t)row * D;
  float ss = 0.f;
  for (int c = threadIdx.x; c < D; c += 256) { float v = xr[c]; ss += v * v; }
  #pragma unroll
  for (int d = 1; d < 64; d <<= 1) ss += __shfl_xor(ss, d, 64);
  __shared__ float part[4];
  if ((threadIdx.x & 63) == 0) part[threadIdx.x >> 6] = ss;
  __syncthreads();
  float tot = part[0] + part[1] + part[2] + part[3];
  float scale = rsqrtf(tot / (float)D + 1e-6f);
  u16* orow = out + (size_t)row * D;
  for (int c = threadIdx.x; c < D; c += 256) orow[c] = f2bf(xr[c] * scale * w[c]);
}

// ---------------------------------------------------------------- 8-phase GEMM, tile 256 x TN (TN=256 or 128)
// C = A(bf16 [M][K]) @ Bt(bf16 [N][K])^T + bias. 512 threads, 8 waves (2M x 4N).
// LDS: 2 bufs x (A[256][64] + B[TN][64]) bf16, XOR-swizzled 16B chunks:
//   LDS[r][c] = G[r][c ^ (r&7)], linear gload_lds dest + pre-swizzled source.
// Stage order per phase p: [A0,B0,A1,B1] of tile t+1 (loads/event: TN=256: 2,2,2,2; TN=128: 2,1,2,1).
// Quadrants: p0: A1xB1 of tile t-1; p1: A0xB0; p2: A1xB0; p3: A0xB1 (of tile t).
// vmcnt = loads in last-3 stage-events: TN=256: {6,6,6,6}; TN=128: {5,4,5,4}.
// Tile id: bijective XCD-chunked remap, bm-fast (same-bn blocks share an XCD L2).
// MODE 0: bf16 store; 1: f32; 2: f32 +=; 3: gelu->bf16; 4: f32 scatter rows; 5: silu(gate)*v bf16
template <int MODE, int TN>
__global__ __launch_bounds__(512, 2) void gemm8_k(
    const u16* __restrict__ A, const u16* __restrict__ Bt, const float* __restrict__ bias,
    void* __restrict__ outp, const int* __restrict__ rowmap, const u16* __restrict__ gatebuf,
    int nbm, int N, int K) {
  constexpr int NBW = (TN == 256) ? 4 : 2;     // B col-frags per wave
  constexpr int NBn = (TN == 256) ? 2 : 1;     // B frags per quadrant
  constexpr unsigned BBUFSZ = (TN == 256) ? 32768u : 16384u;
  __shared__ __align__(16) u16 LDS[(TN == 256) ? 65536 : 49152];
  const int tid = threadIdx.x;
  const int w = tid >> 6, lane = tid & 63;
  const int wm = w >> 2, wn = w & 3;
  const int lr = lane & 15, lk = lane >> 4, lrm = lr & 7;
  const int NT = K >> 6;
  const size_t Kb = (size_t)K * 2;
  const int l8 = lane >> 3, l7 = lane & 7;
  const int schunk = l7 ^ l8;                 // pre-swizzled source chunk

  // -------- bijective XCD-chunked tile decode (m204), bm-fast in-chunk
  const int nwg = gridDim.x;
  {
  }
  const int q8 = nwg >> 3, r8 = nwg & 7;
  const int xcd = blockIdx.x & 7, ord = blockIdx.x >> 3;
  const int id = (xcd < r8 ? xcd * (q8 + 1) : r8 * (q8 + 1) + (xcd - r8) * q8) + ord;
  const int bm = id % nbm, bn = id / nbm;

  const unsigned wm16lr = (unsigned)(wm * 16 + lr) * 128u;
  const unsigned wn16lr = (unsigned)(wn * 16 + lr) * 128u;
  unsigned ch[2];
  ch[0] = (unsigned)(((lk) ^ lrm) << 4);
  ch[1] = (unsigned)(((4 + lk) ^ lrm) << 4);
  const char* LB = (const char*)&LDS[0];

  f32x4 acc[8][NBW];
  #pragma unroll
  for (int f = 0; f < 8; f++)
    #pragma unroll
    for (int n = 0; n < NBW; n++) { acc[f][n][0]=0.f; acc[f][n][1]=0.f; acc[f][n][2]=0.f; acc[f][n][3]=0.f; }

  const char* Ab = (const char*)A;
  const char* Bb = (const char*)Bt;
  u16* LDSp = &LDS[0];

  // stage one half-tile. isB: operand; half: 0/1; tt: K-tile; bb: lds buf
  auto STAGE = [&](int isB, int half, int tt, int bb) {
    long k0b = (long)tt * 128;
    if (!isB) {
      int rb = bm * 256 + half * 128;
      #pragma unroll
      for (int i = 0; i < 2; i++) {
        int r0 = half * 128 + i * 64 + w * 8;
        int gr = rb + i * 64 + w * 8 + l8;
        const char* src = Ab + (size_t)gr * Kb + k0b + schunk * 16;
        unsigned dst = (unsigned)bb * 32768u + (unsigned)r0 * 128u;
        gload_lds16((const u16*)src, LDSp + dst / 2);
      }
    } else if constexpr (TN == 256) {
      int rb = bn * 256 + half * 128;
      #pragma unroll
      for (int i = 0; i < 2; i++) {
        int r0 = half * 128 + i * 64 + w * 8;
        int gr = rb + i * 64 + w * 8 + l8;
        if (gr >= N) gr = N - 1;
        const char* src = Bb + (size_t)gr * Kb + k0b + schunk * 16;
        unsigned dst = 65536u + (unsigned)bb * BBUFSZ + (unsigned)r0 * 128u;
        gload_lds16((const u16*)src, LDSp + dst / 2);
      }
    } else {
      int r0 = half * 64 + w * 8;
      int gr = bn * 128 + half * 64 + w * 8 + l8;
      if (gr >= N) gr = N - 1;
      const char* src = Bb + (size_t)gr * Kb + k0b + schunk * 16;
      unsigned dst = 65536u + (unsigned)bb * BBUFSZ + (unsigned)r0 * 128u;
      gload_lds16((const u16*)src, LDSp + dst / 2);
    }
  };

#define QREAD(FA, NB, ABUF, BBUF)                                                   \
    _Pragma("unroll") for (int f = 0; f < 4; f++) {                                 \
      _Pragma("unroll") for (int kk = 0; kk < 2; kk++) {                            \
        unsigned ad = (ABUF) + (unsigned)((FA) + f) * 4096u + wm16lr + ch[kk];      \
        af[f][kk] = *(const bf16x8*)(LB + ad);                                      \
      }                                                                             \
    }                                                                               \
    _Pragma("unroll") for (int n = 0; n < NBn; n++) {                               \
      _Pragma("unroll") for (int kk = 0; kk < 2; kk++) {                            \
        unsigned ad = 65536u + (BBUF) + (unsigned)((NB) + n) * 8192u + wn16lr + ch[kk]; \
        bfr[n][kk] = *(const bf16x8*)(LB + ad);                                     \
      }                                                                             \
    }

#define QMFMA(FA, NB)                                                               \
    __builtin_amdgcn_s_setprio(1);                                                  \
    _Pragma("unroll") for (int kk = 0; kk < 2; kk++) {                              \
      _Pragma("unroll") for (int f = 0; f < 4; f++) {                               \
        _Pragma("unroll") for (int n = 0; n < NBn; n++) {                           \
          acc[(FA) + f][(NB) + n] = __builtin_amdgcn_mfma_f32_16x16x32_bf16(        \
              af[f][kk], bfr[n][kk], acc[(FA) + f][(NB) + n], 0, 0, 0);             \
        }                                                                           \
      }                                                                             \
    }                                                                               \
    __builtin_amdgcn_s_setprio(0);

#define SYNC1(VM)                                                                   \
    asm volatile("s_waitcnt vmcnt(" #VM ")" ::: "memory");                          \
    __builtin_amdgcn_s_barrier();                                                   \
    asm volatile("s_waitcnt lgkmcnt(0)" ::: "memory");                              \
    __builtin_amdgcn_sched_barrier(0);

#define SYNC2                                                                       \
    __builtin_amdgcn_s_barrier();                                                   \
    __builtin_amdgcn_sched_barrier(0);

  // prologue: stage tile 0 fully into buf 0
  STAGE(0, 0, 0, 0);
  STAGE(1, 0, 0, 0);
  STAGE(0, 1, 0, 0);
  STAGE(1, 1, 0, 0);

  for (int t = 0; t < NT; t++) {
    const unsigned aob  = (unsigned)(t & 1) * 32768u;
    const unsigned aobp = aob ^ 32768u;
    const unsigned bob  = (unsigned)(t & 1) * BBUFSZ;
    const unsigned bobp = bob ^ BBUFSZ;
    const int bb1 = (t + 1) & 1;
    const int tn = (t + 1 < NT) ? (t + 1) : 0;         // clamp dummy stage source
    // ---- phase 0: quadrant A1xB1 of tile t-1
    {
      bf16x8 af[4][2], bfr[NBn][2];
      if (t > 0) { QREAD(4, NBn, aobp, bobp) }
      STAGE(0, 0, tn, bb1);
      if constexpr (TN == 256) { SYNC1(6) } else { SYNC1(5) }
      if (t > 0) { QMFMA(4, NBn) }
      SYNC2
    }
    // ---- phase 1: A0xB0 of tile t
    {
      bf16x8 af[4][2], bfr[NBn][2];
      QREAD(0, 0, aob, bob)
      STAGE(1, 0, tn, bb1);
      if constexpr (TN == 256) { SYNC1(6) } else { SYNC1(4) }
      QMFMA(0, 0)
      SYNC2
    }
    // ---- phase 2: A1xB0
    {
      bf16x8 af[4][2], bfr[NBn][2];
      QREAD(4, 0, aob, bob)
      STAGE(0, 1, tn, bb1);
      if constexpr (TN == 256) { SYNC1(6) } else { SYNC1(5) }
      QMFMA(4, 0)
      SYNC2
    }
    // ---- phase 3: A0xB1
    {
      bf16x8 af[4][2], bfr[NBn][2];
      QREAD(0, NBn, aob, bob)
      STAGE(1, 1, tn, bb1);
      if constexpr (TN == 256) { SYNC1(6) } else { SYNC1(4) }
      QMFMA(0, NBn)
      SYNC2
    }
  }
  // tail: A1xB1 of tile NT-1
  {
    bf16x8 af[4][2], bfr[NBn][2];
    const unsigned aob = (unsigned)((NT - 1) & 1) * 32768u;
    const unsigned bob = (unsigned)((NT - 1) & 1) * BBUFSZ;
    QREAD(4, NBn, aob, bob)
    asm volatile("s_waitcnt lgkmcnt(0)" ::: "memory");
    __builtin_amdgcn_sched_barrier(0);
    QMFMA(4, NBn)
  }
#undef QREAD
#undef QMFMA
#undef SYNC1
#undef SYNC2

  // epilogue
  #pragma unroll
  for (int n = 0; n < NBW; n++) {
    int Cc = bn * TN + n * 64 + wn * 16 + lr;
    bool ok = (Cc < N);
    float bv = (bias && ok) ? bias[Cc] : 0.f;
    #pragma unroll
    for (int f = 0; f < 8; f++) {
      #pragma unroll
      for (int j = 0; j < 4; j++) {
        int R = bm * 256 + f * 32 + wm * 16 + lk * 4 + j;
        float v = acc[f][n][j] + bv;
        if (ok) {
          if (MODE == 0) {
            ((u16*)outp)[(size_t)R * N + Cc] = f2bf(v);
          } else if (MODE == 1) {
            ((float*)outp)[(size_t)R * N + Cc] = v;
          } else if (MODE == 2) {
            ((float*)outp)[(size_t)R * N + Cc] += v;
          } else if (MODE == 3) {
            ((u16*)outp)[(size_t)R * N + Cc] = f2bf(gelu_tanh(v));
          } else if (MODE == 4) {
            int orow = rowmap[R];
            ((float*)outp)[(size_t)orow * N + Cc] = v;
          } else {
            float g = bf2f(gatebuf[(size_t)R * N + Cc]);
            float sg = g / (1.f + __expf(-g));
            ((u16*)outp)[(size_t)R * N + Cc] = f2bf(sg * v);
          }
        }
      }
    }
  }
}

// ---------------------------------------------------------------- windowed attention with fused RoPE
__global__ __launch_bounds__(256, 2) void attn_k(
    const u16* __restrict__ qkv, u16* __restrict__ outO,
    const float* __restrict__ cosr, const float* __restrict__ sinr) {
  __shared__ u16 Qs[64 * 104];
  __shared__ u16 Ks[64 * 104];
  __shared__ u16 Vt[80 * 72];
  __shared__ u16 Ps[64 * 72];
  const int w = blockIdx.x, hd = blockIdx.y;
  const int tid = threadIdx.x;
  const u16* base = qkv + (size_t)w * 64 * 3840 + hd * 80;

  for (int idx = tid; idx < 64 * 96; idx += 256) {
    int r = idx / 96, c = idx - r * 96;
    u16 qv = 0, kv = 0;
    if (c < 80) {
      int tokg = w * 64 + r;
      float cc = cosr[(size_t)tokg * 80 + c], ss = sinr[(size_t)tokg * 80 + c];
      int cp = (c < 40) ? c + 40 : c - 40;
      float sgn = (c < 40) ? -1.f : 1.f;
      float q  = bf2f(base[(size_t)r * 3840 + c]);
      float qp = bf2f(base[(size_t)r * 3840 + cp]);
      float k  = bf2f(base[(size_t)r * 3840 + 1280 + c]);
      float kp = bf2f(base[(size_t)r * 3840 + 1280 + cp]);
      qv = f2bf(q * cc + sgn * qp * ss);
      kv = f2bf(k * cc + sgn * kp * ss);
    }
    Qs[r * 104 + c] = qv;
    Ks[r * 104 + c] = kv;
  }
  for (int idx = tid; idx < 80 * 64; idx += 256) {
    int d = idx >> 6, kt = idx & 63;
    Vt[d * 72 + kt] = base[(size_t)kt * 3840 + 2560 + d];
  }
  __syncthreads();

  const int lane = tid & 63, wv = tid >> 6;
  const int lr = lane & 15, lk = lane >> 4;
  const float sc = 0.11180339887498949f;  // 80^-0.5

  f32x4 sfrag[4];
  #pragma unroll
  for (int f = 0; f < 4; f++) { sfrag[f][0]=0.f; sfrag[f][1]=0.f; sfrag[f][2]=0.f; sfrag[f][3]=0.f; }
  bf16x8 aq[3];
  #pragma unroll
  for (int ks = 0; ks < 3; ks++) aq[ks] = *(const bf16x8*)&Qs[(wv * 16 + lr) * 104 + ks * 32 + lk * 8];
  #pragma unroll
  for (int fn = 0; fn < 4; fn++) {
    #pragma unroll
    for (int ks = 0; ks < 3; ks++) {
      bf16x8 bk = *(const bf16x8*)&Ks[(fn * 16 + lr) * 104 + ks * 32 + lk * 8];
      sfrag[fn] = __builtin_amdgcn_mfma_f32_16x16x32_bf16(aq[ks], bk, sfrag[fn], 0, 0, 0);
    }
  }

  float inv[4];
  #pragma unroll
  for (int j = 0; j < 4; j++) {
    float mx = -1e30f;
    #pragma unroll
    for (int fn = 0; fn < 4; fn++) mx = fmaxf(mx, sfrag[fn][j] * sc);
    #pragma unroll
    for (int d = 1; d < 16; d <<= 1) mx = fmaxf(mx, __shfl_xor(mx, d, 64));
    float sum = 0.f;
    #pragma unroll
    for (int fn = 0; fn < 4; fn++) {
      float e = __expf(sfrag[fn][j] * sc - mx);
      Ps[(wv * 16 + lk * 4 + j) * 72 + fn * 16 + lr] = f2bf(e);
      sum += e;
    }
    #pragma unroll
    for (int d = 1; d < 16; d <<= 1) sum += __shfl_xor(sum, d, 64);
    inv[j] = 1.0f / sum;
  }
  __syncthreads();

  bf16x8 ap[2];
  #pragma unroll
  for (int ks = 0; ks < 2; ks++) ap[ks] = *(const bf16x8*)&Ps[(wv * 16 + lr) * 72 + ks * 32 + lk * 8];
  f32x4 of[5];
  #pragma unroll
  for (int f = 0; f < 5; f++) { of[f][0]=0.f; of[f][1]=0.f; of[f][2]=0.f; of[f][3]=0.f; }
  #pragma unroll
  for (int fn2 = 0; fn2 < 5; fn2++) {
    #pragma unroll
    for (int ks = 0; ks < 2; ks++) {
      bf16x8 bv = *(const bf16x8*)&Vt[(fn2 * 16 + lr) * 72 + ks * 32 + lk * 8];
      of[fn2] = __builtin_amdgcn_mfma_f32_16x16x32_bf16(ap[ks], bv, of[fn2], 0, 0, 0);
    }
  }

  #pragma unroll
  for (int fn2 = 0; fn2 < 5; fn2++) {
    #pragma unroll
    for (int j = 0; j < 4; j++) {
      int q = wv * 16 + lk * 4 + j;
      int d = fn2 * 16 + lr;
      outO[((size_t)(w * 64 + q)) * 1280 + hd * 80 + d] = f2bf(of[fn2][j] * inv[j]);
    }
  }
}

// ---------------------------------------------------------------- host
extern "C" void kernel_launch(void* const* d_in, const int* in_sizes, int n_in,
                              void* d_out, int out_size, void* d_ws, size_t ws_size,
                              hipStream_t stream) {
  (void)in_sizes; (void)n_in; (void)out_size; (void)ws_size;
  const float* pv   = (const float*)d_in[0];
  const float* cosi = (const float*)d_in[1];
  const float* sini = (const float*)d_in[2];
  const int*   wi   = (const int*)d_in[3];
  const float* Wp   = (const float*)d_in[4];
  const float* n1w  = (const float*)d_in[5];
  const float* qkvw = (const float*)d_in[6];
  const float* qkvb = (const float*)d_in[7];
  const float* pw   = (const float*)d_in[8];
  const float* pb   = (const float*)d_in[9];
  const float* n2w  = (const float*)d_in[10];
  const float* gw   = (const float*)d_in[11];
  const float* gb   = (const float*)d_in[12];
  const float* uw   = (const float*)d_in[13];
  const float* ub   = (const float*)d_in[14];
  const float* dw   = (const float*)d_in[15];
  const float* db   = (const float*)d_in[16];
  const float* mnw  = (const float*)d_in[17];
  const float* ml1w = (const float*)d_in[18];
  const float* ml1b = (const float*)d_in[19];
  const float* ml2w = (const float*)d_in[20];
  const float* ml2b = (const float*)d_in[21];
  const float* dnw  = (const float*)d_in[22];
  const float* dl1w = (const float*)d_in[23];
  const float* dl1b = (const float*)d_in[24];
  const float* dl2w = (const float*)d_in[25];
  const float* dl2b = (const float*)d_in[26];
  float* outv = (float*)d_out;
  char* ws = (char*)d_ws;

  size_t off = 0;
  float* h    = (float*)(ws + off); off += (size_t)NTOK * HID_ * 4;      // 84MB
  float* cosr = (float*)(ws + off); off += (size_t)NTOK * 80 * 4;
  float* sinr = (float*)(ws + off); off += (size_t)NTOK * 80 * 4;
  u16*  xb    = (u16*)(ws + off);  off += (size_t)NTOK * HID_ * 2;       // 42MB
  u16*  bufA  = (u16*)(ws + off);  off += (size_t)NTOK * 3840 * 2;       // 126MB
  u16*  bufB  = (u16*)(ws + off);  off += (size_t)NTOK * INTER_ * 2;     // 113MB
  u16*  bufC  = (u16*)(ws + off);  off += (size_t)NTOK * HID_ * 2;       // 42MB
  u16*  Wt    = (u16*)(ws + off);  off += (size_t)BIGD * BIGD * 2;       // 52.5MB

  dim3 B256(256), B512(512);
  #define TW(src, K_, N_) twt_k<<<dim3((N_) / 32, (K_) / 32), B256, 0, stream>>>((src), Wt, (K_), (N_))
  #define G8(MODE, TN_, Abuf, bias_, out_, rmap_, gate_, M_, N_, K_)                      \
    gemm8_k<MODE, TN_><<<dim3(((M_) / 256) * (((N_) + (TN_) - 1) / (TN_))), B512, 0, stream>>>( \
        (Abuf), Wt, (bias_), (out_), (rmap_), (gate_), (M_) / 256, (N_), (K_))

  // gather pixel rows + cos/sin
  gather_pv_k<<<(NTOK * 384 + 255) / 256, B256, 0, stream>>>(pv, wi, bufA);
  gather_cs_k<<<(NTOK * 20 + 255) / 256, B256, 0, stream>>>(cosi, sini, wi, cosr, sinr);

  // h = pv_g @ W_patch   (f32 out)
  TW(Wp, 1536, HID_);
  G8(1, 128, bufA, nullptr, h, nullptr, nullptr, NTOK, HID_, 1536);

  for (int i = 0; i < 6; i++) {
    // attn
    rmsnorm_k<<<NTOK, B256, 0, stream>>>(h, n1w + (size_t)i * HID_, xb, HID_);
    TW(qkvw + (size_t)i * HID_ * 3840, HID_, 3840);
    G8(0, 256, xb, qkvb + (size_t)i * 3840, bufA, nullptr, nullptr, NTOK, 3840, HID_);
    attn_k<<<dim3(256, 16), B256, 0, stream>>>(bufA, bufC, cosr, sinr);
    TW(pw + (size_t)i * HID_ * HID_, HID_, HID_);
    G8(2, 128, bufC, pb + (size_t)i * HID_, h, nullptr, nullptr, NTOK, HID_, HID_);
    // mlp
    rmsnorm_k<<<NTOK, B256, 0, stream>>>(h, n2w + (size_t)i * HID_, xb, HID_);
    TW(gw + (size_t)i * HID_ * INTER_, HID_, INTER_);
    G8(0, 256, xb, gb + (size_t)i * INTER_, bufB, nullptr, nullptr, NTOK, INTER_, HID_);
    TW(uw + (size_t)i * HID_ * INTER_, HID_, INTER_);
    G8(5, 256, xb, ub + (size_t)i * INTER_, bufA, nullptr, bufB, NTOK, INTER_, HID_);
    TW(dw + (size_t)i * INTER_ * HID_, INTER_, HID_);
    G8(2, 128, bufA, db + (size_t)i * HID_, h, nullptr, nullptr, NTOK, HID_, INTER_);
    // deepstack mergers after layers 2 and 4
    if (i == 2 || i == 4) {
      int j = (i == 2) ? 0 : 1;
      rmsnorm_k<<<NGRP, B256, 0, stream>>>(h, dnw + (size_t)j * BIGD, bufC, BIGD);
      TW(dl1w + (size_t)j * BIGD * BIGD, BIGD, BIGD);
      G8(3, 128, bufC, dl1b + (size_t)j * BIGD, bufA, nullptr, nullptr, NGRP, BIGD, BIGD);
      TW(dl2w + (size_t)j * BIGD * ODIM, BIGD, ODIM);
      G8(4, 128, bufA, dl2b + (size_t)j * ODIM, outv + (size_t)(1 + j) * NGRP * ODIM,
         wi, nullptr, NGRP, ODIM, BIGD);
    }
  }

  // final merger -> plane 0
  rmsnorm_k<<<NTOK, B256, 0, stream>>>(h, mnw, bufC, HID_);
  TW(ml1w, BIGD, BIGD);
  G8(3, 128, bufC, ml1b, bufA, nullptr, nullptr, NGRP, BIGD, BIGD);
  TW(ml2w, BIGD, ODIM);
  G8(4, 128, bufA, ml2b, outv, wi, nullptr, NGRP, ODIM, BIGD);
  #undef TW
  #undef G8
}

// Round 8
// 8911.163 us; speedup vs baseline: 1.6618x; 1.0137x over previous
//
#include <hip/hip_runtime.h>
#include <hip/hip_bf16.h>

typedef unsigned short u16;
typedef __bf16 bf16x8 __attribute__((ext_vector_type(8)));
typedef float   f32x4 __attribute__((ext_vector_type(4)));
typedef unsigned short u16x8 __attribute__((ext_vector_type(8)));

#define NTOK  16384
#define HID_  1280
#define NHEAD 16
#define HD    80
#define INTER_ 3456
#define NGRP  4096
#define ODIM  2048
#define BIGD  5120

static __device__ __forceinline__ u16 f2bf(float f) {
  __hip_bfloat16 h = __float2bfloat16(f);
  return __builtin_bit_cast(u16, h);
}
static __device__ __forceinline__ float bf2f(u16 u) {
  return __bfloat162float(__builtin_bit_cast(__hip_bfloat16, u));
}
static __device__ __forceinline__ float gelu_tanh(float x) {
  float x3 = x * x * x;
  return 0.5f * x * (1.0f + tanhf(0.7978845608028654f * (x + 0.044715f * x3)));
}

// async global->LDS, 16B per lane, dest = wave-uniform base + lane*16
static __device__ __forceinline__ void gload_lds16(const u16* g, u16* l) {
  __builtin_amdgcn_global_load_lds(
      (const __attribute__((address_space(1))) unsigned int*)g,
      (__attribute__((address_space(3))) unsigned int*)l, 16, 0, 0);
}

// ---------------------------------------------------------------- gathers
__global__ __launch_bounds__(256) void gather_pv_k(
    const float* __restrict__ pv, const int* __restrict__ wi, u16* __restrict__ out) {
  int t = blockIdx.x * 256 + threadIdx.x;          // NTOK*384 float4 groups
  if (t >= NTOK * 384) return;
  int i = t / 384, c4 = t - i * 384;
  int s = wi[i >> 2] * 4 + (i & 3);
  float4 v = *(const float4*)(pv + (size_t)s * 1536 + c4 * 4);
  uint2 r;
  r.x = (unsigned)f2bf(v.x) | ((unsigned)f2bf(v.y) << 16);
  r.y = (unsigned)f2bf(v.z) | ((unsigned)f2bf(v.w) << 16);
  *(uint2*)(out + (size_t)i * 1536 + c4 * 4) = r;
}

__global__ __launch_bounds__(256) void gather_cs_k(
    const float* __restrict__ ci, const float* __restrict__ si,
    const int* __restrict__ wi, float* __restrict__ co, float* __restrict__ so) {
  int t = blockIdx.x * 256 + threadIdx.x;          // NTOK*20 float4 groups
  if (t >= NTOK * 20) return;
  int i = t / 20, c4 = t - i * 20;
  int s = wi[i >> 2] * 4 + (i & 3);
  *(float4*)(co + (size_t)i * 80 + c4 * 4) = *(const float4*)(ci + (size_t)s * 80 + c4 * 4);
  *(float4*)(so + (size_t)i * 80 + c4 * 4) = *(const float4*)(si + (size_t)s * 80 + c4 * 4);
}

// ---------------------------------------------------------------- weight f32[K][N] -> bf16[N][K]
__global__ __launch_bounds__(256) void twt_k(
    const float* __restrict__ W, u16* __restrict__ Wt, int K, int N) {
  __shared__ u16 t[32][33];
  int bn = blockIdx.x * 32, bk = blockIdx.y * 32;
  int tx = threadIdx.x & 31, ty = threadIdx.x >> 5;   // ty 0..7
  #pragma unroll
  for (int r = 0; r < 4; r++) {
    int k = bk + ty + r * 8;
    t[tx][ty + r * 8] = f2bf(W[(size_t)k * N + bn + tx]);
  }
  __syncthreads();
  #pragma unroll
  for (int r = 0; r < 4; r++) {
    int n = bn + ty + r * 8;
    Wt[(size_t)n * K + bk + tx] = t[ty + r * 8][tx];
  }
}

// ---------------------------------------------------------------- rmsnorm (f32 in -> bf16 out)
__global__ __launch_bounds__(256) void rmsnorm_k(
    const float* __restrict__ x, const float* __restrict__ w, u16* __restrict__ out, int D) {
  int row = blockIdx.x;
  const float* xr = x + (size_t)row * D;
  float ss = 0.f;
  for (int c = threadIdx.x; c < D; c += 256) { float v = xr[c]; ss += v * v; }
  #pragma unroll
  for (int d = 1; d < 64; d <<= 1) ss += __shfl_xor(ss, d, 64);
  __shared__ float part[4];
  if ((threadIdx.x & 63) == 0) part[threadIdx.x >> 6] = ss;
  __syncthreads();
  float tot = part[0] + part[1] + part[2] + part[3];
  float scale = rsqrtf(tot / (float)D + 1e-6f);
  u16* orow = out + (size_t)row * D;
  for (int c = threadIdx.x; c < D; c += 256) orow[c] = f2bf(xr[c] * scale * w[c]);
}

// ---------------------------------------------------------------- 8-phase GEMM, tile 256 x TN (TN=256 or 128)
// C = A(bf16 [M][K]) @ Bt(bf16 [N][K])^T + bias. 512 threads, 8 waves (2M x 4N).
// LDS: 2 bufs x (A[256][64] + B[TN][64]) bf16, XOR-swizzled 16B chunks:
//   LDS[r][c] = G[r][c ^ (r&7)], linear gload_lds dest + pre-swizzled source.
// Stage order per phase p: [A0,B0,A1,B1] of tile t+1 (loads/event: TN=256: 2,2,2,2; TN=128: 2,1,2,1).
// Quadrants: p0: A1xB1 of tile t-1; p1: A0xB0; p2: A1xB0; p3: A0xB1 (of tile t).
// vmcnt = loads in last-3 stage-events: TN=256: {6,6,6,6}; TN=128: {5,4,5,4}.
// Tile id: bijective XCD-chunked remap, bn-fast in-chunk (co-resident blocks on an
// XCD share the A-panel, which fits the 4MB L2; weights stream from LLC).
// MODE 0: bf16 store; 1: f32; 2: f32 +=; 3: gelu->bf16; 4: f32 scatter rows; 5: silu(gate)*v bf16
template <int MODE, int TN>
__global__ __launch_bounds__(512, 2) void gemm8_k(
    const u16* __restrict__ A, const u16* __restrict__ Bt, const float* __restrict__ bias,
    void* __restrict__ outp, const int* __restrict__ rowmap, const u16* __restrict__ gatebuf,
    int nbn, int N, int K) {
  constexpr int NBW = (TN == 256) ? 4 : 2;     // B col-frags per wave
  constexpr int NBn = (TN == 256) ? 2 : 1;     // B frags per quadrant
  constexpr unsigned BBUFSZ = (TN == 256) ? 32768u : 16384u;
  __shared__ __align__(16) u16 LDS[(TN == 256) ? 65536 : 49152];
  const int tid = threadIdx.x;
  const int w = tid >> 6, lane = tid & 63;
  const int wm = w >> 2, wn = w & 3;
  const int lr = lane & 15, lk = lane >> 4, lrm = lr & 7;
  const int NT = K >> 6;
  const size_t Kb = (size_t)K * 2;
  const int l8 = lane >> 3, l7 = lane & 7;
  const int schunk = l7 ^ l8;                 // pre-swizzled source chunk

  // -------- bijective XCD-chunked tile decode (m204), bn-fast in-chunk
  const int nwg = gridDim.x;
  const int q8 = nwg >> 3, r8 = nwg & 7;
  const int xcd = blockIdx.x & 7, ord = blockIdx.x >> 3;
  const int id = (xcd < r8 ? xcd * (q8 + 1) : r8 * (q8 + 1) + (xcd - r8) * q8) + ord;
  const int bn = id % nbn, bm = id / nbn;

  const unsigned wm16lr = (unsigned)(wm * 16 + lr) * 128u;
  const unsigned wn16lr = (unsigned)(wn * 16 + lr) * 128u;
  unsigned ch[2];
  ch[0] = (unsigned)(((lk) ^ lrm) << 4);
  ch[1] = (unsigned)(((4 + lk) ^ lrm) << 4);
  const char* LB = (const char*)&LDS[0];

  f32x4 acc[8][NBW];
  #pragma unroll
  for (int f = 0; f < 8; f++)
    #pragma unroll
    for (int n = 0; n < NBW; n++) { acc[f][n][0]=0.f; acc[f][n][1]=0.f; acc[f][n][2]=0.f; acc[f][n][3]=0.f; }

  const char* Ab = (const char*)A;
  const char* Bb = (const char*)Bt;
  u16* LDSp = &LDS[0];

  // stage one half-tile. isB: operand; half: 0/1; tt: K-tile; bb: lds buf
  auto STAGE = [&](int isB, int half, int tt, int bb) {
    long k0b = (long)tt * 128;
    if (!isB) {
      int rb = bm * 256 + half * 128;
      #pragma unroll
      for (int i = 0; i < 2; i++) {
        int r0 = half * 128 + i * 64 + w * 8;
        int gr = rb + i * 64 + w * 8 + l8;
        const char* src = Ab + (size_t)gr * Kb + k0b + schunk * 16;
        unsigned dst = (unsigned)bb * 32768u + (unsigned)r0 * 128u;
        gload_lds16((const u16*)src, LDSp + dst / 2);
      }
    } else if constexpr (TN == 256) {
      int rb = bn * 256 + half * 128;
      #pragma unroll
      for (int i = 0; i < 2; i++) {
        int r0 = half * 128 + i * 64 + w * 8;
        int gr = rb + i * 64 + w * 8 + l8;
        if (gr >= N) gr = N - 1;
        const char* src = Bb + (size_t)gr * Kb + k0b + schunk * 16;
        unsigned dst = 65536u + (unsigned)bb * BBUFSZ + (unsigned)r0 * 128u;
        gload_lds16((const u16*)src, LDSp + dst / 2);
      }
    } else {
      int r0 = half * 64 + w * 8;
      int gr = bn * 128 + half * 64 + w * 8 + l8;
      if (gr >= N) gr = N - 1;
      const char* src = Bb + (size_t)gr * Kb + k0b + schunk * 16;
      unsigned dst = 65536u + (unsigned)bb * BBUFSZ + (unsigned)r0 * 128u;
      gload_lds16((const u16*)src, LDSp + dst / 2);
    }
  };

#define QREAD(FA, NB, ABUF, BBUF)                                                   \
    _Pragma("unroll") for (int f = 0; f < 4; f++) {                                 \
      _Pragma("unroll") for (int kk = 0; kk < 2; kk++) {                            \
        unsigned ad = (ABUF) + (unsigned)((FA) + f) * 4096u + wm16lr + ch[kk];      \
        af[f][kk] = *(const bf16x8*)(LB + ad);                                      \
      }                                                                             \
    }                                                                               \
    _Pragma("unroll") for (int n = 0; n < NBn; n++) {                               \
      _Pragma("unroll") for (int kk = 0; kk < 2; kk++) {                            \
        unsigned ad = 65536u + (BBUF) + (unsigned)((NB) + n) * 8192u + wn16lr + ch[kk]; \
        bfr[n][kk] = *(const bf16x8*)(LB + ad);                                     \
      }                                                                             \
    }

#define QMFMA(FA, NB)                                                               \
    __builtin_amdgcn_s_setprio(1);                                                  \
    _Pragma("unroll") for (int kk = 0; kk < 2; kk++) {                              \
      _Pragma("unroll") for (int f = 0; f < 4; f++) {                               \
        _Pragma("unroll") for (int n = 0; n < NBn; n++) {                           \
          acc[(FA) + f][(NB) + n] = __builtin_amdgcn_mfma_f32_16x16x32_bf16(        \
              af[f][kk], bfr[n][kk], acc[(FA) + f][(NB) + n], 0, 0, 0);             \
        }                                                                           \
      }                                                                             \
    }                                                                               \
    __builtin_amdgcn_s_setprio(0);

#define SYNC1(VM)                                                                   \
    asm volatile("s_waitcnt vmcnt(" #VM ")" ::: "memory");                          \
    __builtin_amdgcn_s_barrier();                                                   \
    asm volatile("s_waitcnt lgkmcnt(0)" ::: "memory");                              \
    __builtin_amdgcn_sched_barrier(0);

#define SYNC2                                                                       \
    __builtin_amdgcn_s_barrier();                                                   \
    __builtin_amdgcn_sched_barrier(0);

  // prologue: stage tile 0 fully into buf 0
  STAGE(0, 0, 0, 0);
  STAGE(1, 0, 0, 0);
  STAGE(0, 1, 0, 0);
  STAGE(1, 1, 0, 0);

  for (int t = 0; t < NT; t++) {
    const unsigned aob  = (unsigned)(t & 1) * 32768u;
    const unsigned aobp = aob ^ 32768u;
    const unsigned bob  = (unsigned)(t & 1) * BBUFSZ;
    const unsigned bobp = bob ^ BBUFSZ;
    const int bb1 = (t + 1) & 1;
    const int tn = (t + 1 < NT) ? (t + 1) : 0;         // clamp dummy stage source
    // ---- phase 0: quadrant A1xB1 of tile t-1
    {
      bf16x8 af[4][2], bfr[NBn][2];
      if (t > 0) { QREAD(4, NBn, aobp, bobp) }
      STAGE(0, 0, tn, bb1);
      if constexpr (TN == 256) { SYNC1(6) } else { SYNC1(5) }
      if (t > 0) { QMFMA(4, NBn) }
      SYNC2
    }
    // ---- phase 1: A0xB0 of tile t
    {
      bf16x8 af[4][2], bfr[NBn][2];
      QREAD(0, 0, aob, bob)
      STAGE(1, 0, tn, bb1);
      if constexpr (TN == 256) { SYNC1(6) } else { SYNC1(4) }
      QMFMA(0, 0)
      SYNC2
    }
    // ---- phase 2: A1xB0
    {
      bf16x8 af[4][2], bfr[NBn][2];
      QREAD(4, 0, aob, bob)
      STAGE(0, 1, tn, bb1);
      if constexpr (TN == 256) { SYNC1(6) } else { SYNC1(5) }
      QMFMA(4, 0)
      SYNC2
    }
    // ---- phase 3: A0xB1
    {
      bf16x8 af[4][2], bfr[NBn][2];
      QREAD(0, NBn, aob, bob)
      STAGE(1, 1, tn, bb1);
      if constexpr (TN == 256) { SYNC1(6) } else { SYNC1(4) }
      QMFMA(0, NBn)
      SYNC2
    }
  }
  // tail: A1xB1 of tile NT-1
  {
    bf16x8 af[4][2], bfr[NBn][2];
    const unsigned aob = (unsigned)((NT - 1) & 1) * 32768u;
    const unsigned bob = (unsigned)((NT - 1) & 1) * BBUFSZ;
    QREAD(4, NBn, aob, bob)
    asm volatile("s_waitcnt lgkmcnt(0)" ::: "memory");
    __builtin_amdgcn_sched_barrier(0);
    QMFMA(4, NBn)
  }
#undef QREAD
#undef QMFMA
#undef SYNC1
#undef SYNC2

  // epilogue
  #pragma unroll
  for (int n = 0; n < NBW; n++) {
    int Cc = bn * TN + n * 64 + wn * 16 + lr;
    bool ok = (Cc < N);
    float bv = (bias && ok) ? bias[Cc] : 0.f;
    #pragma unroll
    for (int f = 0; f < 8; f++) {
      #pragma unroll
      for (int j = 0; j < 4; j++) {
        int R = bm * 256 + f * 32 + wm * 16 + lk * 4 + j;
        float v = acc[f][n][j] + bv;
        if (ok) {
          if (MODE == 0) {
            ((u16*)outp)[(size_t)R * N + Cc] = f2bf(v);
          } else if (MODE == 1) {
            ((float*)outp)[(size_t)R * N + Cc] = v;
          } else if (MODE == 2) {
            ((float*)outp)[(size_t)R * N + Cc] += v;
          } else if (MODE == 3) {
            ((u16*)outp)[(size_t)R * N + Cc] = f2bf(gelu_tanh(v));
          } else if (MODE == 4) {
            int orow = rowmap[R];
            ((float*)outp)[(size_t)orow * N + Cc] = v;
          } else {
            float g = bf2f(gatebuf[(size_t)R * N + Cc]);
            float sg = g / (1.f + __expf(-g));
            ((u16*)outp)[(size_t)R * N + Cc] = f2bf(sg * v);
          }
        }
      }
    }
  }
}

// ---------------------------------------------------------------- windowed attention with fused RoPE
__global__ __launch_bounds__(256, 2) void attn_k(
    const u16* __restrict__ qkv, u16* __restrict__ outO,
    const float* __restrict__ cosr, const float* __restrict__ sinr) {
  __shared__ u16 Qs[64 * 104];
  __shared__ u16 Ks[64 * 104];
  __shared__ u16 Vt[80 * 72];
  __shared__ u16 Ps[64 * 72];
  const int w = blockIdx.x, hd = blockIdx.y;
  const int tid = threadIdx.x;
  const u16* base = qkv + (size_t)w * 64 * 3840 + hd * 80;

  for (int idx = tid; idx < 64 * 96; idx += 256) {
    int r = idx / 96, c = idx - r * 96;
    u16 qv = 0, kv = 0;
    if (c < 80) {
      int tokg = w * 64 + r;
      float cc = cosr[(size_t)tokg * 80 + c], ss = sinr[(size_t)tokg * 80 + c];
      int cp = (c < 40) ? c + 40 : c - 40;
      float sgn = (c < 40) ? -1.f : 1.f;
      float q  = bf2f(base[(size_t)r * 3840 + c]);
      float qp = bf2f(base[(size_t)r * 3840 + cp]);
      float k  = bf2f(base[(size_t)r * 3840 + 1280 + c]);
      float kp = bf2f(base[(size_t)r * 3840 + 1280 + cp]);
      qv = f2bf(q * cc + sgn * qp * ss);
      kv = f2bf(k * cc + sgn * kp * ss);
    }
    Qs[r * 104 + c] = qv;
    Ks[r * 104 + c] = kv;
  }
  for (int idx = tid; idx < 80 * 64; idx += 256) {
    int d = idx >> 6, kt = idx & 63;
    Vt[d * 72 + kt] = base[(size_t)kt * 3840 + 2560 + d];
  }
  __syncthreads();

  const int lane = tid & 63, wv = tid >> 6;
  const int lr = lane & 15, lk = lane >> 4;
  const float sc = 0.11180339887498949f;  // 80^-0.5

  f32x4 sfrag[4];
  #pragma unroll
  for (int f = 0; f < 4; f++) { sfrag[f][0]=0.f; sfrag[f][1]=0.f; sfrag[f][2]=0.f; sfrag[f][3]=0.f; }
  bf16x8 aq[3];
  #pragma unroll
  for (int ks = 0; ks < 3; ks++) aq[ks] = *(const bf16x8*)&Qs[(wv * 16 + lr) * 104 + ks * 32 + lk * 8];
  #pragma unroll
  for (int fn = 0; fn < 4; fn++) {
    #pragma unroll
    for (int ks = 0; ks < 3; ks++) {
      bf16x8 bk = *(const bf16x8*)&Ks[(fn * 16 + lr) * 104 + ks * 32 + lk * 8];
      sfrag[fn] = __builtin_amdgcn_mfma_f32_16x16x32_bf16(aq[ks], bk, sfrag[fn], 0, 0, 0);
    }
  }

  float inv[4];
  #pragma unroll
  for (int j = 0; j < 4; j++) {
    float mx = -1e30f;
    #pragma unroll
    for (int fn = 0; fn < 4; fn++) mx = fmaxf(mx, sfrag[fn][j] * sc);
    #pragma unroll
    for (int d = 1; d < 16; d <<= 1) mx = fmaxf(mx, __shfl_xor(mx, d, 64));
    float sum = 0.f;
    #pragma unroll
    for (int fn = 0; fn < 4; fn++) {
      float e = __expf(sfrag[fn][j] * sc - mx);
      Ps[(wv * 16 + lk * 4 + j) * 72 + fn * 16 + lr] = f2bf(e);
      sum += e;
    }
    #pragma unroll
    for (int d = 1; d < 16; d <<= 1) sum += __shfl_xor(sum, d, 64);
    inv[j] = 1.0f / sum;
  }
  __syncthreads();

  bf16x8 ap[2];
  #pragma unroll
  for (int ks = 0; ks < 2; ks++) ap[ks] = *(const bf16x8*)&Ps[(wv * 16 + lr) * 72 + ks * 32 + lk * 8];
  f32x4 of[5];
  #pragma unroll
  for (int f = 0; f < 5; f++) { of[f][0]=0.f; of[f][1]=0.f; of[f][2]=0.f; of[f][3]=0.f; }
  #pragma unroll
  for (int fn2 = 0; fn2 < 5; fn2++) {
    #pragma unroll
    for (int ks = 0; ks < 2; ks++) {
      bf16x8 bv = *(const bf16x8*)&Vt[(fn2 * 16 + lr) * 72 + ks * 32 + lk * 8];
      of[fn2] = __builtin_amdgcn_mfma_f32_16x16x32_bf16(ap[ks], bv, of[fn2], 0, 0, 0);
    }
  }

  #pragma unroll
  for (int fn2 = 0; fn2 < 5; fn2++) {
    #pragma unroll
    for (int j = 0; j < 4; j++) {
      int q = wv * 16 + lk * 4 + j;
      int d = fn2 * 16 + lr;
      outO[((size_t)(w * 64 + q)) * 1280 + hd * 80 + d] = f2bf(of[fn2][j] * inv[j]);
    }
  }
}

// ---------------------------------------------------------------- host
extern "C" void kernel_launch(void* const* d_in, const int* in_sizes, int n_in,
                              void* d_out, int out_size, void* d_ws, size_t ws_size,
                              hipStream_t stream) {
  (void)in_sizes; (void)n_in; (void)out_size; (void)ws_size;
  const float* pv   = (const float*)d_in[0];
  const float* cosi = (const float*)d_in[1];
  const float* sini = (const float*)d_in[2];
  const int*   wi   = (const int*)d_in[3];
  const float* Wp   = (const float*)d_in[4];
  const float* n1w  = (const float*)d_in[5];
  const float* qkvw = (const float*)d_in[6];
  const float* qkvb = (const float*)d_in[7];
  const float* pw   = (const float*)d_in[8];
  const float* pb   = (const float*)d_in[9];
  const float* n2w  = (const float*)d_in[10];
  const float* gw   = (const float*)d_in[11];
  const float* gb   = (const float*)d_in[12];
  const float* uw   = (const float*)d_in[13];
  const float* ub   = (const float*)d_in[14];
  const float* dw   = (const float*)d_in[15];
  const float* db   = (const float*)d_in[16];
  const float* mnw  = (const float*)d_in[17];
  const float* ml1w = (const float*)d_in[18];
  const float* ml1b = (const float*)d_in[19];
  const float* ml2w = (const float*)d_in[20];
  const float* ml2b = (const float*)d_in[21];
  const float* dnw  = (const float*)d_in[22];
  const float* dl1w = (const float*)d_in[23];
  const float* dl1b = (const float*)d_in[24];
  const float* dl2w = (const float*)d_in[25];
  const float* dl2b = (const float*)d_in[26];
  float* outv = (float*)d_out;
  char* ws = (char*)d_ws;

  size_t off = 0;
  float* h    = (float*)(ws + off); off += (size_t)NTOK * HID_ * 4;      // 84MB
  float* cosr = (float*)(ws + off); off += (size_t)NTOK * 80 * 4;
  float* sinr = (float*)(ws + off); off += (size_t)NTOK * 80 * 4;
  u16*  xb    = (u16*)(ws + off);  off += (size_t)NTOK * HID_ * 2;       // 42MB
  u16*  bufA  = (u16*)(ws + off);  off += (size_t)NTOK * 3840 * 2;       // 126MB
  u16*  bufB  = (u16*)(ws + off);  off += (size_t)NTOK * INTER_ * 2;     // 113MB
  u16*  bufC  = (u16*)(ws + off);  off += (size_t)NTOK * HID_ * 2;       // 42MB
  u16*  Wt    = (u16*)(ws + off);  off += (size_t)BIGD * BIGD * 2;       // 52.5MB

  dim3 B256(256), B512(512);
  #define TW(src, K_, N_) twt_k<<<dim3((N_) / 32, (K_) / 32), B256, 0, stream>>>((src), Wt, (K_), (N_))
  #define G8(MODE, TN_, Abuf, bias_, out_, rmap_, gate_, M_, N_, K_)                      \
    gemm8_k<MODE, TN_><<<dim3(((M_) / 256) * (((N_) + (TN_) - 1) / (TN_))), B512, 0, stream>>>( \
        (Abuf), Wt, (bias_), (out_), (rmap_), (gate_), (((N_) + (TN_) - 1) / (TN_)), (N_), (K_))

  // gather pixel rows + cos/sin
  gather_pv_k<<<(NTOK * 384 + 255) / 256, B256, 0, stream>>>(pv, wi, bufA);
  gather_cs_k<<<(NTOK * 20 + 255) / 256, B256, 0, stream>>>(cosi, sini, wi, cosr, sinr);

  // h = pv_g @ W_patch   (f32 out)
  TW(Wp, 1536, HID_);
  G8(1, 128, bufA, nullptr, h, nullptr, nullptr, NTOK, HID_, 1536);

  for (int i = 0; i < 6; i++) {
    // attn
    rmsnorm_k<<<NTOK, B256, 0, stream>>>(h, n1w + (size_t)i * HID_, xb, HID_);
    TW(qkvw + (size_t)i * HID_ * 3840, HID_, 3840);
    G8(0, 256, xb, qkvb + (size_t)i * 3840, bufA, nullptr, nullptr, NTOK, 3840, HID_);
    attn_k<<<dim3(256, 16), B256, 0, stream>>>(bufA, bufC, cosr, sinr);
    TW(pw + (size_t)i * HID_ * HID_, HID_, HID_);
    G8(2, 128, bufC, pb + (size_t)i * HID_, h, nullptr, nullptr, NTOK, HID_, HID_);
    // mlp
    rmsnorm_k<<<NTOK, B256, 0, stream>>>(h, n2w + (size_t)i * HID_, xb, HID_);
    TW(gw + (size_t)i * HID_ * INTER_, HID_, INTER_);
    G8(0, 256, xb, gb + (size_t)i * INTER_, bufB, nullptr, nullptr, NTOK, INTER_, HID_);
    TW(uw + (size_t)i * HID_ * INTER_, HID_, INTER_);
    G8(5, 256, xb, ub + (size_t)i * INTER_, bufA, nullptr, bufB, NTOK, INTER_, HID_);
    TW(dw + (size_t)i * INTER_ * HID_, INTER_, HID_);
    G8(2, 128, bufA, db + (size_t)i * HID_, h, nullptr, nullptr, NTOK, HID_, INTER_);
    // deepstack mergers after layers 2 and 4
    if (i == 2 || i == 4) {
      int j = (i == 2) ? 0 : 1;
      rmsnorm_k<<<NGRP, B256, 0, stream>>>(h, dnw + (size_t)j * BIGD, bufC, BIGD);
      TW(dl1w + (size_t)j * BIGD * BIGD, BIGD, BIGD);
      G8(3, 128, bufC, dl1b + (size_t)j * BIGD, bufA, nullptr, nullptr, NGRP, BIGD, BIGD);
      TW(dl2w + (size_t)j * BIGD * ODIM, BIGD, ODIM);
      G8(4, 128, bufA, dl2b + (size_t)j * ODIM, outv + (size_t)(1 + j) * NGRP * ODIM,
         wi, nullptr, NGRP, ODIM, BIGD);
    }
  }

  // final merger -> plane 0
  rmsnorm_k<<<NTOK, B256, 0, stream>>>(h, mnw, bufC, HID_);
  TW(ml1w, BIGD, BIGD);
  G8(3, 128, bufC, ml1b, bufA, nullptr, nullptr, NGRP, BIGD, BIGD);
  TW(ml2w, BIGD, ODIM);
  G8(4, 128, bufA, ml2b, outv, wi, nullptr, NGRP, ODIM, BIGD);
  #undef TW
  #undef G8
}

// Round 10
// 8650.359 us; speedup vs baseline: 1.7119x; 1.0301x over previous
//
#include <hip/hip_runtime.h>
#include <hip/hip_bf16.h>

typedef unsigned short u16;
typedef __bf16 bf16x8 __attribute__((ext_vector_type(8)));
typedef float   f32x4 __attribute__((ext_vector_type(4)));
typedef unsigned short u16x8 __attribute__((ext_vector_type(8)));

#define NTOK  16384
#define HID_  1280
#define NHEAD 16
#define HD    80
#define INTER_ 3456
#define NGRP  4096
#define ODIM  2048
#define BIGD  5120

static __device__ __forceinline__ u16 f2bf(float f) {
  __hip_bfloat16 h = __float2bfloat16(f);
  return __builtin_bit_cast(u16, h);
}
static __device__ __forceinline__ float bf2f(u16 u) {
  return __bfloat162float(__builtin_bit_cast(__hip_bfloat16, u));
}
static __device__ __forceinline__ float gelu_tanh(float x) {
  float y = 0.7978845608028654f * (x + 0.044715f * x * x * x);
  float t = 1.0f - 2.0f / (1.0f + __expf(2.0f * y));   // tanh(y)
  return 0.5f * x * (1.0f + t);
}

// async global->LDS, 16B per lane, dest = wave-uniform base + lane*16
static __device__ __forceinline__ void gload_lds16(const u16* g, u16* l) {
  __builtin_amdgcn_global_load_lds(
      (const __attribute__((address_space(1))) unsigned int*)g,
      (__attribute__((address_space(3))) unsigned int*)l, 16, 0, 0);
}

// ---------------------------------------------------------------- gathers
__global__ __launch_bounds__(256) void gather_pv_k(
    const float* __restrict__ pv, const int* __restrict__ wi, u16* __restrict__ out) {
  int t = blockIdx.x * 256 + threadIdx.x;          // NTOK*384 float4 groups
  if (t >= NTOK * 384) return;
  int i = t / 384, c4 = t - i * 384;
  int s = wi[i >> 2] * 4 + (i & 3);
  float4 v = *(const float4*)(pv + (size_t)s * 1536 + c4 * 4);
  uint2 r;
  r.x = (unsigned)f2bf(v.x) | ((unsigned)f2bf(v.y) << 16);
  r.y = (unsigned)f2bf(v.z) | ((unsigned)f2bf(v.w) << 16);
  *(uint2*)(out + (size_t)i * 1536 + c4 * 4) = r;
}

__global__ __launch_bounds__(256) void gather_cs_k(
    const float* __restrict__ ci, const float* __restrict__ si,
    const int* __restrict__ wi, float* __restrict__ co, float* __restrict__ so) {
  int t = blockIdx.x * 256 + threadIdx.x;          // NTOK*20 float4 groups
  if (t >= NTOK * 20) return;
  int i = t / 20, c4 = t - i * 20;
  int s = wi[i >> 2] * 4 + (i & 3);
  *(float4*)(co + (size_t)i * 80 + c4 * 4) = *(const float4*)(ci + (size_t)s * 80 + c4 * 4);
  *(float4*)(so + (size_t)i * 80 + c4 * 4) = *(const float4*)(si + (size_t)s * 80 + c4 * 4);
}

// ---------------------------------------------------------------- weight f32[K][N] -> bf16[N][K]
__global__ __launch_bounds__(256) void twt_k(
    const float* __restrict__ W, u16* __restrict__ Wt, int K, int N) {
  __shared__ u16 t[32][33];
  int bn = blockIdx.x * 32, bk = blockIdx.y * 32;
  int tx = threadIdx.x & 31, ty = threadIdx.x >> 5;   // ty 0..7
  #pragma unroll
  for (int r = 0; r < 4; r++) {
    int k = bk + ty + r * 8;
    t[tx][ty + r * 8] = f2bf(W[(size_t)k * N + bn + tx]);
  }
  __syncthreads();
  #pragma unroll
  for (int r = 0; r < 4; r++) {
    int n = bn + ty + r * 8;
    Wt[(size_t)n * K + bk + tx] = t[ty + r * 8][tx];
  }
}

// ---------------------------------------------------------------- rmsnorm (f32 in -> bf16 out)
__global__ __launch_bounds__(256) void rmsnorm_k(
    const float* __restrict__ x, const float* __restrict__ w, u16* __restrict__ out, int D) {
  int row = blockIdx.x;
  const float* xr = x + (size_t)row * D;
  float ss = 0.f;
  for (int c = threadIdx.x; c < D; c += 256) { float v = xr[c]; ss += v * v; }
  #pragma unroll
  for (int d = 1; d < 64; d <<= 1) ss += __shfl_xor(ss, d, 64);
  __shared__ float part[4];
  if ((threadIdx.x & 63) == 0) part[threadIdx.x >> 6] = ss;
  __syncthreads();
  float tot = part[0] + part[1] + part[2] + part[3];
  float scale = rsqrtf(tot / (float)D + 1e-6f);
  u16* orow = out + (size_t)row * D;
  for (int c = threadIdx.x; c < D; c += 256) orow[c] = f2bf(xr[c] * scale * w[c]);
}

// ---------------------------------------------------------------- 8-phase GEMM, tile TM x 256 (TM=256 or 128)
// C = A(bf16 [M][K]) @ Bt(bf16 [N][K])^T + bias. 512 threads, 8 waves (2M x 4N).
// Wave tile: (TM/2) rows x 64 cols. TM=128 raises MFMA:ds_read ratio for small-N shapes
// (acc[4][4], 32 MFMA / 16 reads per K-tile vs 20 reads at the old TN=128).
// LDS: 2 bufs x (A[TM][64] + B[256][64]) bf16, XOR-swizzled 16B chunks:
//   LDS[r][c] = G[r][c ^ (r&7)], linear gload_lds dest + pre-swizzled source.
// Stage order per phase p: [A0,B0,A1,B1] of tile t+1; loads/event TM=256: 2,2,2,2; TM=128: 1,2,1,2.
// Quadrants (Ahalf,Bhalf): p0:(1,1) of tile t-1; p1:(0,0); p2:(1,0); p3:(0,1) of tile t.
// vmcnt = loads in last-3 stage-events: TM=256: {6,6,6,6}; TM=128: {4,5,4,5}.
// Tile id: bijective XCD-chunked remap, bn-fast in-chunk.
// MODE 0: bf16 store; 1: f32; 2: f32 +=; 3: gelu->bf16; 4: f32 scatter rows; 5: silu(gate)*v bf16
template <int MODE, int TM>
__global__ __launch_bounds__(512, 2) void gemm8_k(
    const u16* __restrict__ A, const u16* __restrict__ Bt, const float* __restrict__ bias,
    void* __restrict__ outp, const int* __restrict__ rowmap, const u16* __restrict__ gatebuf,
    int nbn, int N, int K) {
  constexpr int MF = TM / 64;                 // A frags per quadrant (4 or 2)
  constexpr unsigned ABUFSZ = (unsigned)TM * 128u;   // bytes per A buf
  constexpr unsigned BBASE = 2u * ABUFSZ;
  __shared__ __align__(16) u16 LDS[(2 * (int)ABUFSZ + 65536) / 2];
  const int tid = threadIdx.x;
  const int w = tid >> 6, lane = tid & 63;
  const int wm = w >> 2, wn = w & 3;
  const int lr = lane & 15, lk = lane >> 4, lrm = lr & 7;
  const int NT = K >> 6;
  const size_t Kb = (size_t)K * 2;
  const int l8 = lane >> 3, l7 = lane & 7;
  const int schunk = l7 ^ l8;                 // pre-swizzled source chunk

  // -------- bijective XCD-chunked tile decode (m204), bn-fast in-chunk
  const int nwg = gridDim.x;
  const int q8 = nwg >> 3, r8 = nwg & 7;
  const int xcd = blockIdx.x & 7, ord = blockIdx.x >> 3;
  const int id = (xcd < r8 ? xcd * (q8 + 1) : r8 * (q8 + 1) + (xcd - r8) * q8) + ord;
  const int bn = id % nbn, bm = id / nbn;

  const unsigned wm16lr = (unsigned)(wm * 16 + lr) * 128u;
  const unsigned wn16lr = (unsigned)(wn * 16 + lr) * 128u;
  unsigned ch[2];
  ch[0] = (unsigned)(((lk) ^ lrm) << 4);
  ch[1] = (unsigned)(((4 + lk) ^ lrm) << 4);
  const char* LB = (const char*)&LDS[0];

  f32x4 acc[2 * MF][4];
  #pragma unroll
  for (int f = 0; f < 2 * MF; f++)
    #pragma unroll
    for (int n = 0; n < 4; n++) { acc[f][n][0]=0.f; acc[f][n][1]=0.f; acc[f][n][2]=0.f; acc[f][n][3]=0.f; }

  const char* Ab = (const char*)A;
  const char* Bb = (const char*)Bt;
  u16* LDSp = &LDS[0];

  // stage one half-tile. isB: operand; half: 0/1; tt: K-tile; bb: lds buf
  auto STAGE = [&](int isB, int half, int tt, int bb) {
    long k0b = (long)tt * 128;
    if (!isB) {
      if constexpr (TM == 256) {
        int rb = bm * 256 + half * 128;
        #pragma unroll
        for (int i = 0; i < 2; i++) {
          int r0 = half * 128 + i * 64 + w * 8;
          int gr = rb + i * 64 + w * 8 + l8;
          const char* src = Ab + (size_t)gr * Kb + k0b + schunk * 16;
          unsigned dst = (unsigned)bb * ABUFSZ + (unsigned)r0 * 128u;
          gload_lds16((const u16*)src, LDSp + dst / 2);
        }
      } else {
        int r0 = half * 64 + w * 8;
        int gr = bm * 128 + half * 64 + w * 8 + l8;
        const char* src = Ab + (size_t)gr * Kb + k0b + schunk * 16;
        unsigned dst = (unsigned)bb * ABUFSZ + (unsigned)r0 * 128u;
        gload_lds16((const u16*)src, LDSp + dst / 2);
      }
    } else {
      int rb = bn * 256 + half * 128;
      #pragma unroll
      for (int i = 0; i < 2; i++) {
        int r0 = half * 128 + i * 64 + w * 8;
        int gr = rb + i * 64 + w * 8 + l8;
        if (gr >= N) gr = N - 1;
        const char* src = Bb + (size_t)gr * Kb + k0b + schunk * 16;
        unsigned dst = BBASE + (unsigned)bb * 32768u + (unsigned)r0 * 128u;
        gload_lds16((const u16*)src, LDSp + dst / 2);
      }
    }
  };

#define QREAD(MH, NH, ABUF, BBUF)                                                   \
    _Pragma("unroll") for (int f = 0; f < MF; f++) {                                \
      _Pragma("unroll") for (int kk = 0; kk < 2; kk++) {                            \
        unsigned ad = (ABUF) + (unsigned)((MH) * MF + f) * 4096u + wm16lr + ch[kk]; \
        af[f][kk] = *(const bf16x8*)(LB + ad);                                      \
      }                                                                             \
    }                                                                               \
    _Pragma("unroll") for (int n = 0; n < 2; n++) {                                 \
      _Pragma("unroll") for (int kk = 0; kk < 2; kk++) {                            \
        unsigned ad = BBASE + (BBUF) + (unsigned)((NH) * 2 + n) * 8192u + wn16lr + ch[kk]; \
        bfr[n][kk] = *(const bf16x8*)(LB + ad);                                     \
      }                                                                             \
    }

#define QMFMA(MH, NH)                                                               \
    __builtin_amdgcn_s_setprio(1);                                                  \
    _Pragma("unroll") for (int kk = 0; kk < 2; kk++) {                              \
      _Pragma("unroll") for (int f = 0; f < MF; f++) {                              \
        _Pragma("unroll") for (int n = 0; n < 2; n++) {                             \
          acc[(MH) * MF + f][(NH) * 2 + n] = __builtin_amdgcn_mfma_f32_16x16x32_bf16( \
              af[f][kk], bfr[n][kk], acc[(MH) * MF + f][(NH) * 2 + n], 0, 0, 0);    \
        }                                                                           \
      }                                                                             \
    }                                                                               \
    __builtin_amdgcn_s_setprio(0);

#define SYNC1(VM)                                                                   \
    asm volatile("s_waitcnt vmcnt(" #VM ")" ::: "memory");                          \
    __builtin_amdgcn_s_barrier();                                                   \
    asm volatile("s_waitcnt lgkmcnt(0)" ::: "memory");                              \
    __builtin_amdgcn_sched_barrier(0);

#define SYNC2                                                                       \
    __builtin_amdgcn_s_barrier();                                                   \
    __builtin_amdgcn_sched_barrier(0);

  // prologue: stage tile 0 fully into buf 0 (events: A0,B0,A1,B1)
  STAGE(0, 0, 0, 0);
  STAGE(1, 0, 0, 0);
  STAGE(0, 1, 0, 0);
  STAGE(1, 1, 0, 0);

  for (int t = 0; t < NT; t++) {
    const unsigned aob  = (unsigned)(t & 1) * ABUFSZ;
    const unsigned aobp = aob ^ ABUFSZ;
    const unsigned bob  = (unsigned)(t & 1) * 32768u;
    const unsigned bobp = bob ^ 32768u;
    const int bb1 = (t + 1) & 1;
    const int tn = (t + 1 < NT) ? (t + 1) : 0;         // clamp dummy stage source
    // ---- phase 0: quadrant (A1,B1) of tile t-1
    {
      bf16x8 af[MF][2], bfr[2][2];
      if (t > 0) { QREAD(1, 1, aobp, bobp) }
      STAGE(0, 0, tn, bb1);
      if constexpr (TM == 256) { SYNC1(6) } else { SYNC1(4) }
      if (t > 0) { QMFMA(1, 1) }
      SYNC2
    }
    // ---- phase 1: (A0,B0) of tile t
    {
      bf16x8 af[MF][2], bfr[2][2];
      QREAD(0, 0, aob, bob)
      STAGE(1, 0, tn, bb1);
      if constexpr (TM == 256) { SYNC1(6) } else { SYNC1(5) }
      QMFMA(0, 0)
      SYNC2
    }
    // ---- phase 2: (A1,B0)
    {
      bf16x8 af[MF][2], bfr[2][2];
      QREAD(1, 0, aob, bob)
      STAGE(0, 1, tn, bb1);
      if constexpr (TM == 256) { SYNC1(6) } else { SYNC1(4) }
      QMFMA(1, 0)
      SYNC2
    }
    // ---- phase 3: (A0,B1)
    {
      bf16x8 af[MF][2], bfr[2][2];
      QREAD(0, 1, aob, bob)
      STAGE(1, 1, tn, bb1);
      if constexpr (TM == 256) { SYNC1(6) } else { SYNC1(5) }
      QMFMA(0, 1)
      SYNC2
    }
  }
  // tail: (A1,B1) of tile NT-1
  {
    bf16x8 af[MF][2], bfr[2][2];
    const unsigned aob = (unsigned)((NT - 1) & 1) * ABUFSZ;
    const unsigned bob = (unsigned)((NT - 1) & 1) * 32768u;
    QREAD(1, 1, aob, bob)
    asm volatile("s_waitcnt lgkmcnt(0)" ::: "memory");
    __builtin_amdgcn_sched_barrier(0);
    QMFMA(1, 1)
  }
#undef QREAD
#undef QMFMA
#undef SYNC1
#undef SYNC2

  // epilogue
  #pragma unroll
  for (int nf = 0; nf < 4; nf++) {
    int Cc = bn * 256 + nf * 64 + wn * 16 + lr;
    bool ok = (Cc < N);
    float bv = (bias && ok) ? bias[Cc] : 0.f;
    #pragma unroll
    for (int mf = 0; mf < 2 * MF; mf++) {
      #pragma unroll
      for (int j = 0; j < 4; j++) {
        int R = bm * TM + mf * 32 + wm * 16 + lk * 4 + j;
        float v = acc[mf][nf][j] + bv;
        if (ok) {
          if (MODE == 0) {
            ((u16*)outp)[(size_t)R * N + Cc] = f2bf(v);
          } else if (MODE == 1) {
            ((float*)outp)[(size_t)R * N + Cc] = v;
          } else if (MODE == 2) {
            ((float*)outp)[(size_t)R * N + Cc] += v;
          } else if (MODE == 3) {
            ((u16*)outp)[(size_t)R * N + Cc] = f2bf(gelu_tanh(v));
          } else if (MODE == 4) {
            int orow = rowmap[R];
            ((float*)outp)[(size_t)orow * N + Cc] = v;
          } else {
            float g = bf2f(gatebuf[(size_t)R * N + Cc]);
            float sg = g / (1.f + __expf(-g));
            ((u16*)outp)[(size_t)R * N + Cc] = f2bf(sg * v);
          }
        }
      }
    }
  }
}

// ---------------------------------------------------------------- windowed attention with fused RoPE
__global__ __launch_bounds__(256, 2) void attn_k(
    const u16* __restrict__ qkv, u16* __restrict__ outO,
    const float* __restrict__ cosr, const float* __restrict__ sinr) {
  __shared__ u16 Qs[64 * 104];
  __shared__ u16 Ks[64 * 104];
  __shared__ u16 Vt[80 * 72];
  __shared__ u16 Ps[64 * 72];
  const int w = blockIdx.x, hd = blockIdx.y;
  const int tid = threadIdx.x;
  const u16* base = qkv + (size_t)w * 64 * 3840 + hd * 80;

  for (int idx = tid; idx < 64 * 96; idx += 256) {
    int r = idx / 96, c = idx - r * 96;
    u16 qv = 0, kv = 0;
    if (c < 80) {
      int tokg = w * 64 + r;
      float cc = cosr[(size_t)tokg * 80 + c], ss = sinr[(size_t)tokg * 80 + c];
      int cp = (c < 40) ? c + 40 : c - 40;
      float sgn = (c < 40) ? -1.f : 1.f;
      float q  = bf2f(base[(size_t)r * 3840 + c]);
      float qp = bf2f(base[(size_t)r * 3840 + cp]);
      float k  = bf2f(base[(size_t)r * 3840 + 1280 + c]);
      float kp = bf2f(base[(size_t)r * 3840 + 1280 + cp]);
      qv = f2bf(q * cc + sgn * qp * ss);
      kv = f2bf(k * cc + sgn * kp * ss);
    }
    Qs[r * 104 + c] = qv;
    Ks[r * 104 + c] = kv;
  }
  for (int idx = tid; idx < 80 * 64; idx += 256) {
    int d = idx >> 6, kt = idx & 63;
    Vt[d * 72 + kt] = base[(size_t)kt * 3840 + 2560 + d];
  }
  __syncthreads();

  const int lane = tid & 63, wv = tid >> 6;
  const int lr = lane & 15, lk = lane >> 4;
  const float sc = 0.11180339887498949f;  // 80^-0.5

  f32x4 sfrag[4];
  #pragma unroll
  for (int f = 0; f < 4; f++) { sfrag[f][0]=0.f; sfrag[f][1]=0.f; sfrag[f][2]=0.f; sfrag[f][3]=0.f; }
  bf16x8 aq[3];
  #pragma unroll
  for (int ks = 0; ks < 3; ks++) aq[ks] = *(const bf16x8*)&Qs[(wv * 16 + lr) * 104 + ks * 32 + lk * 8];
  #pragma unroll
  for (int fn = 0; fn < 4; fn++) {
    #pragma unroll
    for (int ks = 0; ks < 3; ks++) {
      bf16x8 bk = *(const bf16x8*)&Ks[(fn * 16 + lr) * 104 + ks * 32 + lk * 8];
      sfrag[fn] = __builtin_amdgcn_mfma_f32_16x16x32_bf16(aq[ks], bk, sfrag[fn], 0, 0, 0);
    }
  }

  float inv[4];
  #pragma unroll
  for (int j = 0; j < 4; j++) {
    float mx = -1e30f;
    #pragma unroll
    for (int fn = 0; fn < 4; fn++) mx = fmaxf(mx, sfrag[fn][j] * sc);
    #pragma unroll
    for (int d = 1; d < 16; d <<= 1) mx = fmaxf(mx, __shfl_xor(mx, d, 64));
    float sum = 0.f;
    #pragma unroll
    for (int fn = 0; fn < 4; fn++) {
      float e = __expf(sfrag[fn][j] * sc - mx);
      Ps[(wv * 16 + lk * 4 + j) * 72 + fn * 16 + lr] = f2bf(e);
      sum += e;
    }
    #pragma unroll
    for (int d = 1; d < 16; d <<= 1) sum += __shfl_xor(sum, d, 64);
    inv[j] = 1.0f / sum;
  }
  __syncthreads();

  bf16x8 ap[2];
  #pragma unroll
  for (int ks = 0; ks < 2; ks++) ap[ks] = *(const bf16x8*)&Ps[(wv * 16 + lr) * 72 + ks * 32 + lk * 8];
  f32x4 of[5];
  #pragma unroll
  for (int f = 0; f < 5; f++) { of[f][0]=0.f; of[f][1]=0.f; of[f][2]=0.f; of[f][3]=0.f; }
  #pragma unroll
  for (int fn2 = 0; fn2 < 5; fn2++) {
    #pragma unroll
    for (int ks = 0; ks < 2; ks++) {
      bf16x8 bv = *(const bf16x8*)&Vt[(fn2 * 16 + lr) * 72 + ks * 32 + lk * 8];
      of[fn2] = __builtin_amdgcn_mfma_f32_16x16x32_bf16(ap[ks], bv, of[fn2], 0, 0, 0);
    }
  }

  #pragma unroll
  for (int fn2 = 0; fn2 < 5; fn2++) {
    #pragma unroll
    for (int j = 0; j < 4; j++) {
      int q = wv * 16 + lk * 4 + j;
      int d = fn2 * 16 + lr;
      outO[((size_t)(w * 64 + q)) * 1280 + hd * 80 + d] = f2bf(of[fn2][j] * inv[j]);
    }
  }
}

// ---------------------------------------------------------------- host
extern "C" void kernel_launch(void* const* d_in, const int* in_sizes, int n_in,
                              void* d_out, int out_size, void* d_ws, size_t ws_size,
                              hipStream_t stream) {
  (void)in_sizes; (void)n_in; (void)out_size; (void)ws_size;
  const float* pv   = (const float*)d_in[0];
  const float* cosi = (const float*)d_in[1];
  const float* sini = (const float*)d_in[2];
  const int*   wi   = (const int*)d_in[3];
  const float* Wp   = (const float*)d_in[4];
  const float* n1w  = (const float*)d_in[5];
  const float* qkvw = (const float*)d_in[6];
  const float* qkvb = (const float*)d_in[7];
  const float* pw   = (const float*)d_in[8];
  const float* pb   = (const float*)d_in[9];
  const float* n2w  = (const float*)d_in[10];
  const float* gw   = (const float*)d_in[11];
  const float* gb   = (const float*)d_in[12];
  const float* uw   = (const float*)d_in[13];
  const float* ub   = (const float*)d_in[14];
  const float* dw   = (const float*)d_in[15];
  const float* db   = (const float*)d_in[16];
  const float* mnw  = (const float*)d_in[17];
  const float* ml1w = (const float*)d_in[18];
  const float* ml1b = (const float*)d_in[19];
  const float* ml2w = (const float*)d_in[20];
  const float* ml2b = (const float*)d_in[21];
  const float* dnw  = (const float*)d_in[22];
  const float* dl1w = (const float*)d_in[23];
  const float* dl1b = (const float*)d_in[24];
  const float* dl2w = (const float*)d_in[25];
  const float* dl2b = (const float*)d_in[26];
  float* outv = (float*)d_out;
  char* ws = (char*)d_ws;

  size_t off = 0;
  float* h    = (float*)(ws + off); off += (size_t)NTOK * HID_ * 4;      // 84MB
  float* cosr = (float*)(ws + off); off += (size_t)NTOK * 80 * 4;
  float* sinr = (float*)(ws + off); off += (size_t)NTOK * 80 * 4;
  u16*  xb    = (u16*)(ws + off);  off += (size_t)NTOK * HID_ * 2;       // 42MB
  u16*  bufA  = (u16*)(ws + off);  off += (size_t)NTOK * 3840 * 2;       // 126MB
  u16*  bufB  = (u16*)(ws + off);  off += (size_t)NTOK * INTER_ * 2;     // 113MB
  u16*  bufC  = (u16*)(ws + off);  off += (size_t)NTOK * HID_ * 2;       // 42MB
  u16*  Wt    = (u16*)(ws + off);  off += (size_t)BIGD * BIGD * 2;       // 52.5MB

  dim3 B256(256), B512(512);
  #define TW(src, K_, N_) twt_k<<<dim3((N_) / 32, (K_) / 32), B256, 0, stream>>>((src), Wt, (K_), (N_))
  #define G8(MODE, TM_, Abuf, bias_, out_, rmap_, gate_, M_, N_, K_)                      \
    gemm8_k<MODE, TM_><<<dim3(((M_) / (TM_)) * (((N_) + 255) / 256)), B512, 0, stream>>>( \
        (Abuf), Wt, (bias_), (out_), (rmap_), (gate_), (((N_) + 255) / 256), (N_), (K_))

  // gather pixel rows + cos/sin
  gather_pv_k<<<(NTOK * 384 + 255) / 256, B256, 0, stream>>>(pv, wi, bufA);
  gather_cs_k<<<(NTOK * 20 + 255) / 256, B256, 0, stream>>>(cosi, sini, wi, cosr, sinr);

  // h = pv_g @ W_patch   (f32 out)
  TW(Wp, 1536, HID_);
  G8(1, 128, bufA, nullptr, h, nullptr, nullptr, NTOK, HID_, 1536);

  for (int i = 0; i < 6; i++) {
    // attn
    rmsnorm_k<<<NTOK, B256, 0, stream>>>(h, n1w + (size_t)i * HID_, xb, HID_);
    TW(qkvw + (size_t)i * HID_ * 3840, HID_, 3840);
    G8(0, 256, xb, qkvb + (size_t)i * 3840, bufA, nullptr, nullptr, NTOK, 3840, HID_);
    attn_k<<<dim3(256, 16), B256, 0, stream>>>(bufA, bufC, cosr, sinr);
    TW(pw + (size_t)i * HID_ * HID_, HID_, HID_);
    G8(2, 128, bufC, pb + (size_t)i * HID_, h, nullptr, nullptr, NTOK, HID_, HID_);
    // mlp
    rmsnorm_k<<<NTOK, B256, 0, stream>>>(h, n2w + (size_t)i * HID_, xb, HID_);
    TW(gw + (size_t)i * HID_ * INTER_, HID_, INTER_);
    G8(0, 256, xb, gb + (size_t)i * INTER_, bufB, nullptr, nullptr, NTOK, INTER_, HID_);
    TW(uw + (size_t)i * HID_ * INTER_, HID_, INTER_);
    G8(5, 256, xb, ub + (size_t)i * INTER_, bufA, nullptr, bufB, NTOK, INTER_, HID_);
    TW(dw + (size_t)i * INTER_ * HID_, INTER_, HID_);
    G8(2, 128, bufA, db + (size_t)i * HID_, h, nullptr, nullptr, NTOK, HID_, INTER_);
    // deepstack mergers after layers 2 and 4
    if (i == 2 || i == 4) {
      int j = (i == 2) ? 0 : 1;
      rmsnorm_k<<<NGRP, B256, 0, stream>>>(h, dnw + (size_t)j * BIGD, bufC, BIGD);
      TW(dl1w + (size_t)j * BIGD * BIGD, BIGD, BIGD);
      G8(3, 128, bufC, dl1b + (size_t)j * BIGD, bufA, nullptr, nullptr, NGRP, BIGD, BIGD);
      TW(dl2w + (size_t)j * BIGD * ODIM, BIGD, ODIM);
      G8(4, 128, bufA, dl2b + (size_t)j * ODIM, outv + (size_t)(1 + j) * NGRP * ODIM,
         wi, nullptr, NGRP, ODIM, BIGD);
    }
  }

  // final merger -> plane 0
  rmsnorm_k<<<NTOK, B256, 0, stream>>>(h, mnw, bufC, HID_);
  TW(ml1w, BIGD, BIGD);
  G8(3, 128, bufC, ml1b, bufA, nullptr, nullptr, NGRP, BIGD, BIGD);
  TW(ml2w, BIGD, ODIM);
  G8(4, 128, bufA, ml2b, outv, wi, nullptr, NGRP, ODIM, BIGD);
  #undef TW
  #undef G8
}

// Round 11
// 8103.046 us; speedup vs baseline: 1.8275x; 1.0675x over previous
//
#include <hip/hip_runtime.h>
#include <hip/hip_bf16.h>

typedef unsigned short u16;
typedef __bf16 bf16x8 __attribute__((ext_vector_type(8)));
typedef float   f32x4 __attribute__((ext_vector_type(4)));
typedef unsigned short u16x8 __attribute__((ext_vector_type(8)));

#define NTOK  16384
#define HID_  1280
#define NHEAD 16
#define HD    80
#define INTER_ 3456
#define NGRP  4096
#define ODIM  2048
#define BIGD  5120

static __device__ __forceinline__ u16 f2bf(float f) {
  __hip_bfloat16 h = __float2bfloat16(f);
  return __builtin_bit_cast(u16, h);
}
static __device__ __forceinline__ float bf2f(u16 u) {
  return __bfloat162float(__builtin_bit_cast(__hip_bfloat16, u));
}
static __device__ __forceinline__ float gelu_tanh(float x) {
  float y = 0.7978845608028654f * (x + 0.044715f * x * x * x);
  float t = 1.0f - 2.0f / (1.0f + __expf(2.0f * y));   // tanh(y)
  return 0.5f * x * (1.0f + t);
}

// async global->LDS, 16B per lane, dest = wave-uniform base + lane*16
static __device__ __forceinline__ void gload_lds16(const u16* g, u16* l) {
  __builtin_amdgcn_global_load_lds(
      (const __attribute__((address_space(1))) unsigned int*)g,
      (__attribute__((address_space(3))) unsigned int*)l, 16, 0, 0);
}

// ---------------------------------------------------------------- gathers
__global__ __launch_bounds__(256) void gather_pv_k(
    const float* __restrict__ pv, const int* __restrict__ wi, u16* __restrict__ out) {
  int t = blockIdx.x * 256 + threadIdx.x;          // NTOK*384 float4 groups
  if (t >= NTOK * 384) return;
  int i = t / 384, c4 = t - i * 384;
  int s = wi[i >> 2] * 4 + (i & 3);
  float4 v = *(const float4*)(pv + (size_t)s * 1536 + c4 * 4);
  uint2 r;
  r.x = (unsigned)f2bf(v.x) | ((unsigned)f2bf(v.y) << 16);
  r.y = (unsigned)f2bf(v.z) | ((unsigned)f2bf(v.w) << 16);
  *(uint2*)(out + (size_t)i * 1536 + c4 * 4) = r;
}

__global__ __launch_bounds__(256) void gather_cs_k(
    const float* __restrict__ ci, const float* __restrict__ si,
    const int* __restrict__ wi, float* __restrict__ co, float* __restrict__ so) {
  int t = blockIdx.x * 256 + threadIdx.x;          // NTOK*20 float4 groups
  if (t >= NTOK * 20) return;
  int i = t / 20, c4 = t - i * 20;
  int s = wi[i >> 2] * 4 + (i & 3);
  *(float4*)(co + (size_t)i * 80 + c4 * 4) = *(const float4*)(ci + (size_t)s * 80 + c4 * 4);
  *(float4*)(so + (size_t)i * 80 + c4 * 4) = *(const float4*)(si + (size_t)s * 80 + c4 * 4);
}

// ---------------------------------------------------------------- weight f32[K][N] -> bf16[N][K]
__global__ __launch_bounds__(256) void twt_k(
    const float* __restrict__ W, u16* __restrict__ Wt, int K, int N) {
  __shared__ u16 t[32][33];
  int bn = blockIdx.x * 32, bk = blockIdx.y * 32;
  int tx = threadIdx.x & 31, ty = threadIdx.x >> 5;   // ty 0..7
  #pragma unroll
  for (int r = 0; r < 4; r++) {
    int k = bk + ty + r * 8;
    t[tx][ty + r * 8] = f2bf(W[(size_t)k * N + bn + tx]);
  }
  __syncthreads();
  #pragma unroll
  for (int r = 0; r < 4; r++) {
    int n = bn + ty + r * 8;
    Wt[(size_t)n * K + bk + tx] = t[ty + r * 8][tx];
  }
}

// ---------------------------------------------------------------- rmsnorm (f32 in -> bf16 out)
__global__ __launch_bounds__(256) void rmsnorm_k(
    const float* __restrict__ x, const float* __restrict__ w, u16* __restrict__ out, int D) {
  int row = blockIdx.x;
  const float* xr = x + (size_t)row * D;
  float ss = 0.f;
  for (int c = threadIdx.x; c < D; c += 256) { float v = xr[c]; ss += v * v; }
  #pragma unroll
  for (int d = 1; d < 64; d <<= 1) ss += __shfl_xor(ss, d, 64);
  __shared__ float part[4];
  if ((threadIdx.x & 63) == 0) part[threadIdx.x >> 6] = ss;
  __syncthreads();
  float tot = part[0] + part[1] + part[2] + part[3];
  float scale = rsqrtf(tot / (float)D + 1e-6f);
  u16* orow = out + (size_t)row * D;
  for (int c = threadIdx.x; c < D; c += 256) orow[c] = f2bf(xr[c] * scale * w[c]);
}

// ---------------------------------------------------------------- 8-phase GEMM, tile TM x 256 (TM=256 or 128)
// C = A(bf16 [M][K]) @ Bt(bf16 [N][K])^T + bias. 512 threads, 8 waves (2M x 4N).
// FRAGMENT-READ DEDUP: register sets afE(A0)/afO(A1)/bfE(B0)/bfO(B1) persist across
// phases; each fragment is read from LDS exactly ONCE per K-tile:
//   p0: no reads (reuse afO,bfO from prev iter p2/p3) -> MFMA(A1,B1) of t-1
//   p1: read afE(A0), bfE(B0) -> MFMA(A0,B0)
//   p2: read afO(A1)          -> MFMA(A1,B0)  (reuse bfE)
//   p3: read bfO(B1)          -> MFMA(A0,B1)  (reuse afE)
// Reads/K-tile/wave: TM=128: 16 (was 32), TM=256: 24 (was 48) -> lifts the LDS-BW
// ceiling on MfmaUtil from 30%/40% to ~60%/~80%.
// LDS: 2 bufs x (A[TM][64] + B[256][64]) bf16, XOR-swizzled 16B chunks:
//   LDS[r][c] = G[r][c ^ (r&7)], linear gload_lds dest + pre-swizzled source.
// Stage order per phase p: [A0,B0,A1,B1] of tile t+1; loads/event TM=256: 2,2,2,2; TM=128: 1,2,1,2.
// vmcnt = loads in last-3 stage-events: TM=256: {6,6,6,6}; TM=128: {4,5,4,5}.
// Tile id: bijective XCD-chunked remap, bn-fast in-chunk.
// MODE 0: bf16 store; 1: f32; 2: f32 +=; 3: gelu->bf16; 4: f32 scatter rows; 5: silu(gate)*v bf16
template <int MODE, int TM>
__global__ __launch_bounds__(512, 2) void gemm8_k(
    const u16* __restrict__ A, const u16* __restrict__ Bt, const float* __restrict__ bias,
    void* __restrict__ outp, const int* __restrict__ rowmap, const u16* __restrict__ gatebuf,
    int nbn, int N, int K) {
  constexpr int MF = TM / 64;                 // A frags per half (4 or 2)
  constexpr unsigned ABUFSZ = (unsigned)TM * 128u;   // bytes per A buf
  constexpr unsigned BBASE = 2u * ABUFSZ;
  __shared__ __align__(16) u16 LDS[(2 * (int)ABUFSZ + 65536) / 2];
  const int tid = threadIdx.x;
  const int w = tid >> 6, lane = tid & 63;
  const int wm = w >> 2, wn = w & 3;
  const int lr = lane & 15, lk = lane >> 4, lrm = lr & 7;
  const int NT = K >> 6;
  const size_t Kb = (size_t)K * 2;
  const int l8 = lane >> 3, l7 = lane & 7;
  const int schunk = l7 ^ l8;                 // pre-swizzled source chunk

  // -------- bijective XCD-chunked tile decode (m204), bn-fast in-chunk
  const int nwg = gridDim.x;
  const int q8 = nwg >> 3, r8 = nwg & 7;
  const int xcd = blockIdx.x & 7, ord = blockIdx.x >> 3;
  const int id = (xcd < r8 ? xcd * (q8 + 1) : r8 * (q8 + 1) + (xcd - r8) * q8) + ord;
  const int bn = id % nbn, bm = id / nbn;

  const unsigned wm16lr = (unsigned)(wm * 16 + lr) * 128u;
  const unsigned wn16lr = (unsigned)(wn * 16 + lr) * 128u;
  unsigned ch[2];
  ch[0] = (unsigned)(((lk) ^ lrm) << 4);
  ch[1] = (unsigned)(((4 + lk) ^ lrm) << 4);
  const char* LB = (const char*)&LDS[0];

  f32x4 acc[2 * MF][4];
  #pragma unroll
  for (int f = 0; f < 2 * MF; f++)
    #pragma unroll
    for (int n = 0; n < 4; n++) { acc[f][n][0]=0.f; acc[f][n][1]=0.f; acc[f][n][2]=0.f; acc[f][n][3]=0.f; }

  const char* Ab = (const char*)A;
  const char* Bb = (const char*)Bt;
  u16* LDSp = &LDS[0];

  // persistent fragment registers (dedup: each LDS fragment read once per K-tile)
  bf16x8 afE[MF][2], afO[MF][2], bfE[2][2], bfO[2][2];

  // stage one half-tile. isB: operand; half: 0/1; tt: K-tile; bb: lds buf
  auto STAGE = [&](int isB, int half, int tt, int bb) {
    long k0b = (long)tt * 128;
    if (!isB) {
      if constexpr (TM == 256) {
        int rb = bm * 256 + half * 128;
        #pragma unroll
        for (int i = 0; i < 2; i++) {
          int r0 = half * 128 + i * 64 + w * 8;
          int gr = rb + i * 64 + w * 8 + l8;
          const char* src = Ab + (size_t)gr * Kb + k0b + schunk * 16;
          unsigned dst = (unsigned)bb * ABUFSZ + (unsigned)r0 * 128u;
          gload_lds16((const u16*)src, LDSp + dst / 2);
        }
      } else {
        int r0 = half * 64 + w * 8;
        int gr = bm * 128 + half * 64 + w * 8 + l8;
        const char* src = Ab + (size_t)gr * Kb + k0b + schunk * 16;
        unsigned dst = (unsigned)bb * ABUFSZ + (unsigned)r0 * 128u;
        gload_lds16((const u16*)src, LDSp + dst / 2);
      }
    } else {
      int rb = bn * 256 + half * 128;
      #pragma unroll
      for (int i = 0; i < 2; i++) {
        int r0 = half * 128 + i * 64 + w * 8;
        int gr = rb + i * 64 + w * 8 + l8;
        if (gr >= N) gr = N - 1;
        const char* src = Bb + (size_t)gr * Kb + k0b + schunk * 16;
        unsigned dst = BBASE + (unsigned)bb * 32768u + (unsigned)r0 * 128u;
        gload_lds16((const u16*)src, LDSp + dst / 2);
      }
    }
  };

#define QREAD_A(DST, MH, ABUF)                                                      \
    _Pragma("unroll") for (int f = 0; f < MF; f++) {                                \
      _Pragma("unroll") for (int kk = 0; kk < 2; kk++) {                            \
        unsigned ad = (ABUF) + (unsigned)((MH) * MF + f) * 4096u + wm16lr + ch[kk]; \
        DST[f][kk] = *(const bf16x8*)(LB + ad);                                     \
      }                                                                             \
    }

#define QREAD_B(DST, NH, BBUF)                                                      \
    _Pragma("unroll") for (int n = 0; n < 2; n++) {                                 \
      _Pragma("unroll") for (int kk = 0; kk < 2; kk++) {                            \
        unsigned ad = BBASE + (BBUF) + (unsigned)((NH) * 2 + n) * 8192u + wn16lr + ch[kk]; \
        DST[n][kk] = *(const bf16x8*)(LB + ad);                                     \
      }                                                                             \
    }

#define QMFMA(AF, BF, MH, NH)                                                       \
    __builtin_amdgcn_s_setprio(1);                                                  \
    _Pragma("unroll") for (int kk = 0; kk < 2; kk++) {                              \
      _Pragma("unroll") for (int f = 0; f < MF; f++) {                              \
        _Pragma("unroll") for (int n = 0; n < 2; n++) {                             \
          acc[(MH) * MF + f][(NH) * 2 + n] = __builtin_amdgcn_mfma_f32_16x16x32_bf16( \
              AF[f][kk], BF[n][kk], acc[(MH) * MF + f][(NH) * 2 + n], 0, 0, 0);     \
        }                                                                           \
      }                                                                             \
    }                                                                               \
    __builtin_amdgcn_s_setprio(0);

#define SYNC1(VM)                                                                   \
    asm volatile("s_waitcnt vmcnt(" #VM ")" ::: "memory");                          \
    __builtin_amdgcn_s_barrier();                                                   \
    asm volatile("s_waitcnt lgkmcnt(0)" ::: "memory");                              \
    __builtin_amdgcn_sched_barrier(0);

#define SYNC2                                                                       \
    __builtin_amdgcn_s_barrier();                                                   \
    __builtin_amdgcn_sched_barrier(0);

  // prologue: stage tile 0 fully into buf 0 (events: A0,B0,A1,B1)
  STAGE(0, 0, 0, 0);
  STAGE(1, 0, 0, 0);
  STAGE(0, 1, 0, 0);
  STAGE(1, 1, 0, 0);

  for (int t = 0; t < NT; t++) {
    const unsigned aob  = (unsigned)(t & 1) * ABUFSZ;
    const unsigned bob  = (unsigned)(t & 1) * 32768u;
    const int bb1 = (t + 1) & 1;
    const int tn = (t + 1 < NT) ? (t + 1) : 0;         // clamp dummy stage source
    // ---- phase 0: (A1,B1) of tile t-1 — no LDS reads, registers held from prev iter
    {
      STAGE(0, 0, tn, bb1);
      if constexpr (TM == 256) { SYNC1(6) } else { SYNC1(4) }
      if (t > 0) { QMFMA(afO, bfO, 1, 1) }
      SYNC2
    }
    // ---- phase 1: (A0,B0) of tile t
    {
      QREAD_A(afE, 0, aob)
      QREAD_B(bfE, 0, bob)
      STAGE(1, 0, tn, bb1);
      if constexpr (TM == 256) { SYNC1(6) } else { SYNC1(5) }
      QMFMA(afE, bfE, 0, 0)
      SYNC2
    }
    // ---- phase 2: (A1,B0) — read only A1, reuse bfE
    {
      QREAD_A(afO, 1, aob)
      STAGE(0, 1, tn, bb1);
      if constexpr (TM == 256) { SYNC1(6) } else { SYNC1(4) }
      QMFMA(afO, bfE, 1, 0)
      SYNC2
    }
    // ---- phase 3: (A0,B1) — read only B1, reuse afE
    {
      QREAD_B(bfO, 1, bob)
      STAGE(1, 1, tn, bb1);
      if constexpr (TM == 256) { SYNC1(6) } else { SYNC1(5) }
      QMFMA(afE, bfO, 0, 1)
      SYNC2
    }
  }
  // tail: (A1,B1) of tile NT-1 — afO/bfO already loaded and waited (last iter p2/p3)
  QMFMA(afO, bfO, 1, 1)
#undef QREAD_A
#undef QREAD_B
#undef QMFMA
#undef SYNC1
#undef SYNC2

  // epilogue
  #pragma unroll
  for (int nf = 0; nf < 4; nf++) {
    int Cc = bn * 256 + nf * 64 + wn * 16 + lr;
    bool ok = (Cc < N);
    float bv = (bias && ok) ? bias[Cc] : 0.f;
    #pragma unroll
    for (int mf = 0; mf < 2 * MF; mf++) {
      #pragma unroll
      for (int j = 0; j < 4; j++) {
        int R = bm * TM + mf * 32 + wm * 16 + lk * 4 + j;
        float v = acc[mf][nf][j] + bv;
        if (ok) {
          if (MODE == 0) {
            ((u16*)outp)[(size_t)R * N + Cc] = f2bf(v);
          } else if (MODE == 1) {
            ((float*)outp)[(size_t)R * N + Cc] = v;
          } else if (MODE == 2) {
            ((float*)outp)[(size_t)R * N + Cc] += v;
          } else if (MODE == 3) {
            ((u16*)outp)[(size_t)R * N + Cc] = f2bf(gelu_tanh(v));
          } else if (MODE == 4) {
            int orow = rowmap[R];
            ((float*)outp)[(size_t)orow * N + Cc] = v;
          } else {
            float g = bf2f(gatebuf[(size_t)R * N + Cc]);
            float sg = g / (1.f + __expf(-g));
            ((u16*)outp)[(size_t)R * N + Cc] = f2bf(sg * v);
          }
        }
      }
    }
  }
}

// ---------------------------------------------------------------- windowed attention with fused RoPE
__global__ __launch_bounds__(256, 2) void attn_k(
    const u16* __restrict__ qkv, u16* __restrict__ outO,
    const float* __restrict__ cosr, const float* __restrict__ sinr) {
  __shared__ u16 Qs[64 * 104];
  __shared__ u16 Ks[64 * 104];
  __shared__ u16 Vt[80 * 72];
  __shared__ u16 Ps[64 * 72];
  const int w = blockIdx.x, hd = blockIdx.y;
  const int tid = threadIdx.x;
  const u16* base = qkv + (size_t)w * 64 * 3840 + hd * 80;

  for (int idx = tid; idx < 64 * 96; idx += 256) {
    int r = idx / 96, c = idx - r * 96;
    u16 qv = 0, kv = 0;
    if (c < 80) {
      int tokg = w * 64 + r;
      float cc = cosr[(size_t)tokg * 80 + c], ss = sinr[(size_t)tokg * 80 + c];
      int cp = (c < 40) ? c + 40 : c - 40;
      float sgn = (c < 40) ? -1.f : 1.f;
      float q  = bf2f(base[(size_t)r * 3840 + c]);
      float qp = bf2f(base[(size_t)r * 3840 + cp]);
      float k  = bf2f(base[(size_t)r * 3840 + 1280 + c]);
      float kp = bf2f(base[(size_t)r * 3840 + 1280 + cp]);
      qv = f2bf(q * cc + sgn * qp * ss);
      kv = f2bf(k * cc + sgn * kp * ss);
    }
    Qs[r * 104 + c] = qv;
    Ks[r * 104 + c] = kv;
  }
  for (int idx = tid; idx < 80 * 64; idx += 256) {
    int d = idx >> 6, kt = idx & 63;
    Vt[d * 72 + kt] = base[(size_t)kt * 3840 + 2560 + d];
  }
  __syncthreads();

  const int lane = tid & 63, wv = tid >> 6;
  const int lr = lane & 15, lk = lane >> 4;
  const float sc = 0.11180339887498949f;  // 80^-0.5

  f32x4 sfrag[4];
  #pragma unroll
  for (int f = 0; f < 4; f++) { sfrag[f][0]=0.f; sfrag[f][1]=0.f; sfrag[f][2]=0.f; sfrag[f][3]=0.f; }
  bf16x8 aq[3];
  #pragma unroll
  for (int ks = 0; ks < 3; ks++) aq[ks] = *(const bf16x8*)&Qs[(wv * 16 + lr) * 104 + ks * 32 + lk * 8];
  #pragma unroll
  for (int fn = 0; fn < 4; fn++) {
    #pragma unroll
    for (int ks = 0; ks < 3; ks++) {
      bf16x8 bk = *(const bf16x8*)&Ks[(fn * 16 + lr) * 104 + ks * 32 + lk * 8];
      sfrag[fn] = __builtin_amdgcn_mfma_f32_16x16x32_bf16(aq[ks], bk, sfrag[fn], 0, 0, 0);
    }
  }

  float inv[4];
  #pragma unroll
  for (int j = 0; j < 4; j++) {
    float mx = -1e30f;
    #pragma unroll
    for (int fn = 0; fn < 4; fn++) mx = fmaxf(mx, sfrag[fn][j] * sc);
    #pragma unroll
    for (int d = 1; d < 16; d <<= 1) mx = fmaxf(mx, __shfl_xor(mx, d, 64));
    float sum = 0.f;
    #pragma unroll
    for (int fn = 0; fn < 4; fn++) {
      float e = __expf(sfrag[fn][j] * sc - mx);
      Ps[(wv * 16 + lk * 4 + j) * 72 + fn * 16 + lr] = f2bf(e);
      sum += e;
    }
    #pragma unroll
    for (int d = 1; d < 16; d <<= 1) sum += __shfl_xor(sum, d, 64);
    inv[j] = 1.0f / sum;
  }
  __syncthreads();

  bf16x8 ap[2];
  #pragma unroll
  for (int ks = 0; ks < 2; ks++) ap[ks] = *(const bf16x8*)&Ps[(wv * 16 + lr) * 72 + ks * 32 + lk * 8];
  f32x4 of[5];
  #pragma unroll
  for (int f = 0; f < 5; f++) { of[f][0]=0.f; of[f][1]=0.f; of[f][2]=0.f; of[f][3]=0.f; }
  #pragma unroll
  for (int fn2 = 0; fn2 < 5; fn2++) {
    #pragma unroll
    for (int ks = 0; ks < 2; ks++) {
      bf16x8 bv = *(const bf16x8*)&Vt[(fn2 * 16 + lr) * 72 + ks * 32 + lk * 8];
      of[fn2] = __builtin_amdgcn_mfma_f32_16x16x32_bf16(ap[ks], bv, of[fn2], 0, 0, 0);
    }
  }

  #pragma unroll
  for (int fn2 = 0; fn2 < 5; fn2++) {
    #pragma unroll
    for (int j = 0; j < 4; j++) {
      int q = wv * 16 + lk * 4 + j;
      int d = fn2 * 16 + lr;
      outO[((size_t)(w * 64 + q)) * 1280 + hd * 80 + d] = f2bf(of[fn2][j] * inv[j]);
    }
  }
}

// ---------------------------------------------------------------- host
extern "C" void kernel_launch(void* const* d_in, const int* in_sizes, int n_in,
                              void* d_out, int out_size, void* d_ws, size_t ws_size,
                              hipStream_t stream) {
  (void)in_sizes; (void)n_in; (void)out_size; (void)ws_size;
  const float* pv   = (const float*)d_in[0];
  const float* cosi = (const float*)d_in[1];
  const float* sini = (const float*)d_in[2];
  const int*   wi   = (const int*)d_in[3];
  const float* Wp   = (const float*)d_in[4];
  const float* n1w  = (const float*)d_in[5];
  const float* qkvw = (const float*)d_in[6];
  const float* qkvb = (const float*)d_in[7];
  const float* pw   = (const float*)d_in[8];
  const float* pb   = (const float*)d_in[9];
  const float* n2w  = (const float*)d_in[10];
  const float* gw   = (const float*)d_in[11];
  const float* gb   = (const float*)d_in[12];
  const float* uw   = (const float*)d_in[13];
  const float* ub   = (const float*)d_in[14];
  const float* dw   = (const float*)d_in[15];
  const float* db   = (const float*)d_in[16];
  const float* mnw  = (const float*)d_in[17];
  const float* ml1w = (const float*)d_in[18];
  const float* ml1b = (const float*)d_in[19];
  const float* ml2w = (const float*)d_in[20];
  const float* ml2b = (const float*)d_in[21];
  const float* dnw  = (const float*)d_in[22];
  const float* dl1w = (const float*)d_in[23];
  const float* dl1b = (const float*)d_in[24];
  const float* dl2w = (const float*)d_in[25];
  const float* dl2b = (const float*)d_in[26];
  float* outv = (float*)d_out;
  char* ws = (char*)d_ws;

  size_t off = 0;
  float* h    = (float*)(ws + off); off += (size_t)NTOK * HID_ * 4;      // 84MB
  float* cosr = (float*)(ws + off); off += (size_t)NTOK * 80 * 4;
  float* sinr = (float*)(ws + off); off += (size_t)NTOK * 80 * 4;
  u16*  xb    = (u16*)(ws + off);  off += (size_t)NTOK * HID_ * 2;       // 42MB
  u16*  bufA  = (u16*)(ws + off);  off += (size_t)NTOK * 3840 * 2;       // 126MB
  u16*  bufB  = (u16*)(ws + off);  off += (size_t)NTOK * INTER_ * 2;     // 113MB
  u16*  bufC  = (u16*)(ws + off);  off += (size_t)NTOK * HID_ * 2;       // 42MB
  u16*  Wt    = (u16*)(ws + off);  off += (size_t)BIGD * BIGD * 2;       // 52.5MB

  dim3 B256(256), B512(512);
  #define TW(src, K_, N_) twt_k<<<dim3((N_) / 32, (K_) / 32), B256, 0, stream>>>((src), Wt, (K_), (N_))
  #define G8(MODE, TM_, Abuf, bias_, out_, rmap_, gate_, M_, N_, K_)                      \
    gemm8_k<MODE, TM_><<<dim3(((M_) / (TM_)) * (((N_) + 255) / 256)), B512, 0, stream>>>( \
        (Abuf), Wt, (bias_), (out_), (rmap_), (gate_), (((N_) + 255) / 256), (N_), (K_))

  // gather pixel rows + cos/sin
  gather_pv_k<<<(NTOK * 384 + 255) / 256, B256, 0, stream>>>(pv, wi, bufA);
  gather_cs_k<<<(NTOK * 20 + 255) / 256, B256, 0, stream>>>(cosi, sini, wi, cosr, sinr);

  // h = pv_g @ W_patch   (f32 out)
  TW(Wp, 1536, HID_);
  G8(1, 128, bufA, nullptr, h, nullptr, nullptr, NTOK, HID_, 1536);

  for (int i = 0; i < 6; i++) {
    // attn
    rmsnorm_k<<<NTOK, B256, 0, stream>>>(h, n1w + (size_t)i * HID_, xb, HID_);
    TW(qkvw + (size_t)i * HID_ * 3840, HID_, 3840);
    G8(0, 256, xb, qkvb + (size_t)i * 3840, bufA, nullptr, nullptr, NTOK, 3840, HID_);
    attn_k<<<dim3(256, 16), B256, 0, stream>>>(bufA, bufC, cosr, sinr);
    TW(pw + (size_t)i * HID_ * HID_, HID_, HID_);
    G8(2, 128, bufC, pb + (size_t)i * HID_, h, nullptr, nullptr, NTOK, HID_, HID_);
    // mlp
    rmsnorm_k<<<NTOK, B256, 0, stream>>>(h, n2w + (size_t)i * HID_, xb, HID_);
    TW(gw + (size_t)i * HID_ * INTER_, HID_, INTER_);
    G8(0, 256, xb, gb + (size_t)i * INTER_, bufB, nullptr, nullptr, NTOK, INTER_, HID_);
    TW(uw + (size_t)i * HID_ * INTER_, HID_, INTER_);
    G8(5, 256, xb, ub + (size_t)i * INTER_, bufA, nullptr, bufB, NTOK, INTER_, HID_);
    TW(dw + (size_t)i * INTER_ * HID_, INTER_, HID_);
    G8(2, 128, bufA, db + (size_t)i * HID_, h, nullptr, nullptr, NTOK, HID_, INTER_);
    // deepstack mergers after layers 2 and 4
    if (i == 2 || i == 4) {
      int j = (i == 2) ? 0 : 1;
      rmsnorm_k<<<NGRP, B256, 0, stream>>>(h, dnw + (size_t)j * BIGD, bufC, BIGD);
      TW(dl1w + (size_t)j * BIGD * BIGD, BIGD, BIGD);
      G8(3, 128, bufC, dl1b + (size_t)j * BIGD, bufA, nullptr, nullptr, NGRP, BIGD, BIGD);
      TW(dl2w + (size_t)j * BIGD * ODIM, BIGD, ODIM);
      G8(4, 128, bufA, dl2b + (size_t)j * ODIM, outv + (size_t)(1 + j) * NGRP * ODIM,
         wi, nullptr, NGRP, ODIM, BIGD);
    }
  }

  // final merger -> plane 0
  rmsnorm_k<<<NTOK, B256, 0, stream>>>(h, mnw, bufC, HID_);
  TW(ml1w, BIGD, BIGD);
  G8(3, 128, bufC, ml1b, bufA, nullptr, nullptr, NGRP, BIGD, BIGD);
  TW(ml2w, BIGD, ODIM);
  G8(4, 128, bufA, ml2b, outv, wi, nullptr, NGRP, ODIM, BIGD);
  #undef TW
  #undef G8
}